// Round 21
// baseline (169.145 us; speedup 1.0000x reference)
//
#include <hip/hip_runtime.h>
#include <hip/hip_bf16.h>
#include <stdint.h>

// Problem dims (fixed)
#define MD    1024      // model dim
#define NHEAD 16
#define HDIM  64
#define BSZ   2
#define SEQL  2048
#define MROWS 4096      // BSZ*SEQL

#define SCL2E 0.18033688011112042f   // (1/sqrt(64)) * log2(e), folded into Wq/bq

typedef __bf16 bf16_t;
typedef __bf16  bf16x8 __attribute__((ext_vector_type(8)));
typedef float   f32x4  __attribute__((ext_vector_type(4)));
typedef float   f32x16 __attribute__((ext_vector_type(16)));

// raw v_exp_f32 via compiler-visible builtin (hazards handled by backend).
// R16's inline-asm version FAILED (absmax 5.5e-2): MFMA->TRANS wait-states
// aren't guaranteed across an asm boundary (rule #18). R17/R18 proved the
// builtin correct AND fast (attn 60.2 -> 48.2us).
#if __has_builtin(__builtin_amdgcn_exp2f)
  #define FEXP2(x) __builtin_amdgcn_exp2f(x)
#else
  #define FEXP2(x) exp2f(x)
#endif

// Async global->LDS, 16B per lane. LDS dest is wave-uniform base (+lane*16 by HW).
__device__ __forceinline__ void gload_lds16(const void* g, void* l) {
  __builtin_amdgcn_global_load_lds((const __attribute__((address_space(1))) void*)g,
                                   (__attribute__((address_space(3))) void*)l,
                                   16, 0, 0);
}

__device__ __forceinline__ unsigned short f2bf(float f) {
  unsigned u = __builtin_bit_cast(unsigned, f);
  u += 0x7fffu + ((u >> 16) & 1u);          // round-to-nearest-even
  return (unsigned short)(u >> 16);
}

// packed 2xf32 -> 2xbf16 in one dword (src0 -> low half)
__device__ __forceinline__ unsigned cvtpk(float a, float b) {
  unsigned r;
  asm("v_cvt_pk_bf16_f32 %0, %1, %2" : "=v"(r) : "v"(a), "v"(b));
  return r;
}

// ---------------- consolidated convert ----------------
// grid 16387: [0,12288) X (4096 each), [12288,16384) W (1024 each; Wq scaled),
// 16384: bq*SCL2E -> bqs ; 16385/16386: nmask[b] = sum(1-mask[b][:])
__global__ __launch_bounds__(256)
void cvt_all(const float* __restrict__ q, const float* __restrict__ k, const float* __restrict__ v,
             const float* __restrict__ wq, const float* __restrict__ wk,
             const float* __restrict__ wv, const float* __restrict__ wo,
             const float* __restrict__ mask, const float* __restrict__ bq,
             unsigned short* __restrict__ xq, unsigned short* __restrict__ xk, unsigned short* __restrict__ xv,
             unsigned short* __restrict__ wqb, unsigned short* __restrict__ wkb,
             unsigned short* __restrict__ wvb, unsigned short* __restrict__ wob,
             float* __restrict__ bqs, float* __restrict__ nmask) {
  int bx = blockIdx.x;
  if (bx >= 16384) {
    if (bx == 16384) {                    // bqs = bq * SCL2E (1024 floats)
      int i = threadIdx.x;
      float4 val = ((const float4*)bq)[i];
      float4 o;
      o.x = val.x * SCL2E; o.y = val.y * SCL2E; o.z = val.z * SCL2E; o.w = val.w * SCL2E;
      ((float4*)bqs)[i] = o;
    } else {                              // nmask[b]
      int b = bx - 16385;
      const float* mp = mask + b * SEQL + threadIdx.x * 8;
      float s = 0.0f;
#pragma unroll
      for (int j = 0; j < 8; ++j) s += 1.0f - mp[j];
      for (int d = 1; d < 64; d <<= 1) s += __shfl_xor(s, d);
      __shared__ float wsum[4];
      if ((threadIdx.x & 63) == 0) wsum[threadIdx.x >> 6] = s;
      __syncthreads();
      if (threadIdx.x == 0) nmask[b] = wsum[0] + wsum[1] + wsum[2] + wsum[3];
    }
    return;
  }
  const float* in; unsigned short* out; int i;
  float scale = 1.0f;
  if (bx < 12288) {
    int t = bx >> 12;
    in  = (t == 0) ? q : (t == 1) ? k : v;
    out = (t == 0) ? xq : (t == 1) ? xk : xv;
    i = (bx & 4095) * 256 + threadIdx.x;
  } else {
    int t = (bx - 12288) >> 10;
    in  = (t == 0) ? wq : (t == 1) ? wk : (t == 2) ? wv : wo;
    out = (t == 0) ? wqb : (t == 1) ? wkb : (t == 2) ? wvb : wob;
    if (t == 0) scale = SCL2E;
    i = (bx & 1023) * 256 + threadIdx.x;
  }
  float4 val = ((const float4*)in)[i];
  ushort4 o;
  o.x = f2bf(val.x * scale); o.y = f2bf(val.y * scale);
  o.z = f2bf(val.z * scale); o.w = f2bf(val.w * scale);
  ((ushort4*)out)[i] = o;
}

// ---------------- GEMM: C[m,n] = sum_k A[m,k]*B[n,k] + bias[n] ----------------
// 128x128 tile, BK=64, 4 waves (2x2 of 64x64), 16x16x32 bf16 MFMA.
// SHARED BUFFER IS PASSED IN (declared once per kernel!) — 3 template
// instantiations in one kernel would otherwise each get their own static
// 32KB LDS (R13: LDS_Block_Size=98304 -> 1 block/CU -> 70us).
// MODE: 0 = bf16 row-major [m][n], optional runtime row-mask;
//       1 = f32 row-major;
//       2 = bf16 V in PV(32x32x16) B-frag layout, row-masked;
//       3 = bf16 K in QKt(32x32x16) A-frag layout, row-masked.
template<int MODE>
__device__ __forceinline__ void gemm_body(char* __restrict__ sm,
                                          const bf16_t* __restrict__ A,
                                          const bf16_t* __restrict__ Bm,
                                          const float*  __restrict__ bias,
                                          const float*  __restrict__ mask,
                                          void* __restrict__ Cout, int tile) {
  char* lsA = sm;
  char* lsB = sm + 16384;
  const int tid  = threadIdx.x;
  const int lane = tid & 63;
  const int wv   = tid >> 6;
  const int wm   = wv >> 1, wn = wv & 1;
  const int m0   = (tile >> 3) << 7;   // 32 m-tiles
  const int n0   = (tile & 7)  << 7;   // 8 n-tiles
  const int l15  = lane & 15;
  const int g16  = (lane >> 4) << 4;   // k-group byte base

  f32x4 acc[4][4] = {};

  for (int kk = 0; kk < MD; kk += 64) {
#pragma unroll
    for (int i = 0; i < 4; ++i) {
      int ch  = (wv << 2) + i;
      int o   = ch * 1024 + (lane << 4);
      int row = o >> 7;
      int scb = (o & 127) ^ ((row & 7) << 4);   // pre-swizzled source column byte
      const char* gA = (const char*)A  + (((size_t)(m0 + row) * MD + kk) << 1) + scb;
      const char* gB = (const char*)Bm + (((size_t)(n0 + row) * MD + kk) << 1) + scb;
      gload_lds16(gA, lsA + ch * 1024);
      gload_lds16(gB, lsB + ch * 1024);
    }
    __syncthreads();
#pragma unroll
    for (int s = 0; s < 2; ++s) {
      bf16x8 af[4], bfv[4];
#pragma unroll
      for (int mi = 0; mi < 4; ++mi) {
        int r  = (wm << 6) + (mi << 4) + l15;
        int cb = (g16 + (s << 6)) ^ ((r & 7) << 4);
        af[mi] = *(const bf16x8*)(lsA + (r << 7) + cb);
      }
#pragma unroll
      for (int ni = 0; ni < 4; ++ni) {
        int r  = (wn << 6) + (ni << 4) + l15;
        int cb = (g16 + (s << 6)) ^ ((r & 7) << 4);
        bfv[ni] = *(const bf16x8*)(lsB + (r << 7) + cb);
      }
      __builtin_amdgcn_s_setprio(1);
#pragma unroll
      for (int mi = 0; mi < 4; ++mi)
#pragma unroll
        for (int ni = 0; ni < 4; ++ni)
          acc[mi][ni] = __builtin_amdgcn_mfma_f32_16x16x32_bf16(af[mi], bfv[ni], acc[mi][ni], 0, 0, 0);
      __builtin_amdgcn_s_setprio(0);
    }
    __syncthreads();
  }

  // epilogue: C/D layout col = lane&15, row = (lane>>4)*4 + reg
  float bvv[4];
#pragma unroll
  for (int ni = 0; ni < 4; ++ni) bvv[ni] = bias[n0 + (wn << 6) + (ni << 4) + l15];
#pragma unroll
  for (int mi = 0; mi < 4; ++mi) {
    int m = m0 + (wm << 6) + (mi << 4) + ((lane >> 4) << 2);  // token rows m..m+3
    float4 mk = {1.0f, 1.0f, 1.0f, 1.0f};
    if constexpr (MODE == 2 || MODE == 3) mk = *(const float4*)&mask[m];
    if constexpr (MODE == 0) { if (mask) mk = *(const float4*)&mask[m]; }
#pragma unroll
    for (int ni = 0; ni < 4; ++ni) {
      int col = n0 + (wn << 6) + (ni << 4) + l15;
      if constexpr (MODE == 2) {
        // V PV-B-frag layout; 4 consecutive kv -> 4 contiguous elems (8B store)
        int b2 = m >> 11; int kv = m & 2047;
        int hh = col >> 6; int dd = col & 63;
        int dl = (dd >> 5) & 1; int dcol = dd & 31;
        size_t base = (size_t)((b2 << 4) + hh) * 131072 + (size_t)(kv >> 5) * 2048
                    + (size_t)((((kv >> 4) & 1) << 1) + dl) * 512
                    + (size_t)((((kv >> 3) & 1) << 5) + dcol) * 8 + (kv & 7);
        ushort4 pk;
        pk.x = f2bf((acc[mi][ni][0] + bvv[ni]) * mk.x);
        pk.y = f2bf((acc[mi][ni][1] + bvv[ni]) * mk.y);
        pk.z = f2bf((acc[mi][ni][2] + bvv[ni]) * mk.z);
        pk.w = f2bf((acc[mi][ni][3] + bvv[ni]) * mk.w);
        *(ushort4*)((unsigned short*)Cout + base) = pk;
      } else if constexpr (MODE == 3) {
        // K QKt-A-frag layout; 4 consecutive kv -> stride-8 scalar stores
        int b2 = m >> 11; int kv = m & 2047;
        int hh = col >> 6; int dd = col & 63;
        size_t base = (size_t)((b2 << 4) + hh) * 131072 + (size_t)(kv >> 5) * 2048
                    + (size_t)(dd >> 4) * 512
                    + (size_t)((((dd >> 3) & 1) << 5) + (kv & 31)) * 8 + (dd & 7);
#pragma unroll
        for (int r = 0; r < 4; ++r)
          ((unsigned short*)Cout)[base + ((size_t)r << 3)] =
              f2bf((acc[mi][ni][r] + bvv[ni]) * ((const float*)&mk)[r]);
      } else {
#pragma unroll
        for (int r = 0; r < 4; ++r) {
          float vv = acc[mi][ni][r] + bvv[ni];
          if constexpr (MODE == 0) vv *= ((const float*)&mk)[r];
          if constexpr (MODE == 1) ((float*)Cout)[(size_t)(m + r) * MD + col] = vv;
          else                     ((bf16_t*)Cout)[(size_t)(m + r) * MD + col] = (bf16_t)vv;
        }
      }
    }
  }
}

// fused QKV (768 blocks = 3/CU): Q row-major pre-scaled; K -> Kf frags; V -> Vf frags.
// ONE shared buffer for all three instantiations (32KB total).
__global__ __launch_bounds__(256, 3)
void gemm_qkv(const bf16_t* __restrict__ xq, const bf16_t* __restrict__ xk, const bf16_t* __restrict__ xv,
              const bf16_t* __restrict__ wq, const bf16_t* __restrict__ wk, const bf16_t* __restrict__ wv_,
              const float* __restrict__ bqs, const float* __restrict__ bk, const float* __restrict__ bv,
              const float* __restrict__ mask,
              bf16_t* __restrict__ Qo, bf16_t* __restrict__ Kfo, bf16_t* __restrict__ Vfo) {
  __shared__ __align__(1024) char sm[32768];
  int t = blockIdx.x & 255;
  int g = blockIdx.x >> 8;
  if (g == 0)      gemm_body<0>(sm, xq, wq,  bqs, nullptr, Qo,  t);
  else if (g == 1) gemm_body<3>(sm, xk, wk,  bk,  mask,    Kfo, t);
  else             gemm_body<2>(sm, xv, wv_, bv,  mask,    Vfo, t);
}

// output projection, 64x128 tiles -> 512 blocks = 2 blocks/CU.
__global__ __launch_bounds__(256, 2)
void gemm_out64(const bf16_t* __restrict__ A, const bf16_t* __restrict__ Bm,
                const float* __restrict__ bias, float* __restrict__ C) {
  __shared__ __align__(1024) char sm[24576];
  char* lsA = sm;           // 64 rows x 128B
  char* lsB = sm + 8192;    // 128 rows x 128B
  const int tile = (int)blockIdx.x;
  const int m0   = (tile >> 3) << 6;   // 64 m-tiles
  const int n0   = (tile & 7)  << 7;   // 8 n-tiles
  const int tid  = threadIdx.x;
  const int lane = tid & 63;
  const int wv   = tid >> 6;
  const int l15  = lane & 15;
  const int g16  = (lane >> 4) << 4;

  f32x4 acc[4][2] = {};

  for (int kk = 0; kk < MD; kk += 64) {
#pragma unroll
    for (int i = 0; i < 6; ++i) {
      int ch = wv * 6 + i;             // 24 chunks: 0-7 A, 8-23 B
      if (ch < 8) {
        int o   = ch * 1024 + (lane << 4);
        int row = o >> 7;
        int scb = (o & 127) ^ ((row & 7) << 4);
        gload_lds16((const char*)A + (((size_t)(m0 + row) * MD + kk) << 1) + scb,
                    lsA + ch * 1024);
      } else {
        int cl  = ch - 8;
        int o   = cl * 1024 + (lane << 4);
        int row = o >> 7;
        int scb = (o & 127) ^ ((row & 7) << 4);
        gload_lds16((const char*)Bm + (((size_t)(n0 + row) * MD + kk) << 1) + scb,
                    lsB + cl * 1024);
      }
    }
    __syncthreads();
#pragma unroll
    for (int s = 0; s < 2; ++s) {
      bf16x8 af[4], bfv[2];
#pragma unroll
      for (int mi = 0; mi < 4; ++mi) {
        int r  = (mi << 4) + l15;
        int cb = (g16 + (s << 6)) ^ ((r & 7) << 4);
        af[mi] = *(const bf16x8*)(lsA + (r << 7) + cb);
      }
#pragma unroll
      for (int ni = 0; ni < 2; ++ni) {
        int r  = (wv << 5) + (ni << 4) + l15;
        int cb = (g16 + (s << 6)) ^ ((r & 7) << 4);
        bfv[ni] = *(const bf16x8*)(lsB + (r << 7) + cb);
      }
      __builtin_amdgcn_s_setprio(1);
#pragma unroll
      for (int mi = 0; mi < 4; ++mi)
#pragma unroll
        for (int ni = 0; ni < 2; ++ni)
          acc[mi][ni] = __builtin_amdgcn_mfma_f32_16x16x32_bf16(af[mi], bfv[ni], acc[mi][ni], 0, 0, 0);
      __builtin_amdgcn_s_setprio(0);
    }
    __syncthreads();
  }

  float bvv[2];
#pragma unroll
  for (int ni = 0; ni < 2; ++ni) bvv[ni] = bias[n0 + (wv << 5) + (ni << 4) + l15];
#pragma unroll
  for (int mi = 0; mi < 4; ++mi) {
    int m = m0 + (mi << 4) + ((lane >> 4) << 2);
#pragma unroll
    for (int ni = 0; ni < 2; ++ni) {
      int col = n0 + (wv << 5) + (ni << 4) + l15;
#pragma unroll
      for (int r = 0; r < 4; ++r)
        C[(size_t)(m + r) * MD + col] = acc[mi][ni][r] + bvv[ni];
    }
  }
}

// ---------------- flash attention: all-fragment 32x32, KV-SPLIT BY BLOCKS ---
// grid 1024 = b(2)*half(2)*h(16)*qtile(16), XCD swizzle; block 256 = 4 waves,
// each wave owns 32 q and sweeps its block's kv-HALF (32 chunks). 4096 waves
// = 4 blocks/CU = 4 waves/SIMD (2x the R18 TLP). launch_bounds(256,4):
// VGPR cap 128, we use ~72 -> NO spill (R17's within-block split spilled at
// launch_bounds(512,4)). No-max softmax partials are additive: blocks write
// f32 O-partials + l-partials (no normalize); combine kernel finishes.
// Each block's 4 waves still convoy over the same chunk stream (L1 reuse).
__global__ __launch_bounds__(256, 4)
void attn_kernel(const bf16_t* __restrict__ Q, const bf16_t* __restrict__ Kf,
                 const bf16_t* __restrict__ Vf,
                 float* __restrict__ O0, float* __restrict__ O1,
                 float* __restrict__ L0, float* __restrict__ L1) {
  int bid = (int)blockIdx.x;
  int lb  = (bid & 7) * 128 + (bid >> 3);   // 1024 = 8 x 128, bijective
  const int tid  = threadIdx.x;
  const int lane = tid & 63;
  const int w    = tid >> 6;
  const int qt   = lb & 15;
  const int h    = (lb >> 4) & 15;
  const int half = (lb >> 8) & 1;
  const int b    = lb >> 9;
  const int q0w  = (qt << 7) + (w << 5);
  const int l31  = lane & 31;
  const int hi   = lane >> 5;

  // Q B-frags: lane holds Q[q=l31][d = s4*16 + hi*8 + j]
  bf16x8 qa[4];
  {
    const bf16_t* qp = Q + (size_t)(b * SEQL + q0w + l31) * MD + h * HDIM + (hi << 3);
#pragma unroll
    for (int s4 = 0; s4 < 4; ++s4) qa[s4] = *(const bf16x8*)(qp + (s4 << 4));
  }

  const bf16_t* KfB = Kf + (size_t)((b << 4) + h) * 131072;
  const bf16_t* VfB = Vf + (size_t)((b << 4) + h) * 131072;
  const int c0 = half << 5;

  f32x16 oacc0 = {};   // d 0-31
  f32x16 oacc1 = {};   // d 32-63
  float lrun = 0.0f;

  bf16x8 kA[4], vA[4], kB[4], vB[4];

  auto LDKV = [&](int c, bf16x8* kf, bf16x8* vf) {
    const bf16_t* kp = KfB + (size_t)c * 2048 + (lane << 3);
    const bf16_t* vp = VfB + (size_t)c * 2048 + (lane << 3);
#pragma unroll
    for (int s4 = 0; s4 < 4; ++s4) kf[s4] = *(const bf16x8*)(kp + (s4 << 9));
#pragma unroll
    for (int u = 0; u < 4; ++u)   vf[u] = *(const bf16x8*)(vp + (u << 9));
  };

  auto BLK = [&](bf16x8* kf, bf16x8* vf) {
    f32x16 sacc = {};
    __builtin_amdgcn_s_setprio(1);
#pragma unroll
    for (int s4 = 0; s4 < 4; ++s4)
      sacc = __builtin_amdgcn_mfma_f32_32x32x16_bf16(kf[s4], qa[s4], sacc, 0, 0, 0);
    __builtin_amdgcn_s_setprio(0);
    float e[16];
#pragma unroll
    for (int r = 0; r < 16; ++r) e[r] = FEXP2(sacc[r]);
    lrun += ((e[0] + e[1]) + (e[2] + e[3])) + ((e[4] + e[5]) + (e[6] + e[7]))
          + ((e[8] + e[9]) + (e[10] + e[11])) + ((e[12] + e[13]) + (e[14] + e[15]));
    // P -> PV A-frags (kv 0-15 and 16-31) via cvt_pk + permlane32_swap
    unsigned x1 = cvtpk(e[0], e[1]),  x2 = cvtpk(e[2], e[3]);
    unsigned y1 = cvtpk(e[4], e[5]),  y2 = cvtpk(e[6], e[7]);
    unsigned z1 = cvtpk(e[8], e[9]),  z2 = cvtpk(e[10], e[11]);
    unsigned w1 = cvtpk(e[12], e[13]), w2 = cvtpk(e[14], e[15]);
    asm("v_permlane32_swap_b32 %0, %1" : "+v"(x1), "+v"(y1));
    asm("v_permlane32_swap_b32 %0, %1" : "+v"(x2), "+v"(y2));
    asm("v_permlane32_swap_b32 %0, %1" : "+v"(z1), "+v"(w1));
    asm("v_permlane32_swap_b32 %0, %1" : "+v"(z2), "+v"(w2));
    union { unsigned u[4]; bf16x8 v; } p0, p1;
    p0.u[0] = x1; p0.u[1] = x2; p0.u[2] = y1; p0.u[3] = y2;
    p1.u[0] = z1; p1.u[1] = z2; p1.u[2] = w1; p1.u[3] = w2;
    __builtin_amdgcn_s_setprio(1);
    oacc0 = __builtin_amdgcn_mfma_f32_32x32x16_bf16(p0.v, vf[0], oacc0, 0, 0, 0);
    oacc1 = __builtin_amdgcn_mfma_f32_32x32x16_bf16(p0.v, vf[1], oacc1, 0, 0, 0);
    oacc0 = __builtin_amdgcn_mfma_f32_32x32x16_bf16(p1.v, vf[2], oacc0, 0, 0, 0);
    oacc1 = __builtin_amdgcn_mfma_f32_32x32x16_bf16(p1.v, vf[3], oacc1, 0, 0, 0);
    __builtin_amdgcn_s_setprio(0);
  };

  LDKV(c0, kA, vA);
  for (int ii = 0; ii < 16; ++ii) {
    LDKV(c0 + (ii << 1) + 1, kB, vB);
    BLK(kA, vA);
    LDKV(c0 + (ii << 1) + 2, kA, vA);   // last prefetch overruns into next
    BLK(kB, vB);                        // half/pad (unused -> harmless)
  }

  // partial epilogue: no normalize; f32 O-partials + per-q l-partials
  lrun += __shfl_xor(lrun, 32);
  float* Op = half ? O1 : O0;
  float* Lp = half ? L1 : L0;
#pragma unroll
  for (int r = 0; r < 16; ++r) {
    int q = (r & 3) + ((r >> 2) << 3) + (hi << 2);
    size_t ro = (size_t)(b * SEQL + q0w + q) * MD + h * HDIM;
    Op[ro + l31]      = oacc0[r];
    Op[ro + 32 + l31] = oacc1[r];
  }
  if (lane < 32) Lp[(size_t)((b << 4) + h) * SEQL + q0w + l31] = lrun;
}

// combine: attn = (O0+O1) / (l0+l1-nmask[b]), f32 -> bf16. 4096 blocks x 256.
__global__ __launch_bounds__(256)
void combine_kernel(const float* __restrict__ O0, const float* __restrict__ O1,
                    const float* __restrict__ L0, const float* __restrict__ L1,
                    const float* __restrict__ nmask, unsigned short* __restrict__ attn) {
  int idx  = (int)blockIdx.x * 256 + threadIdx.x;   // 1,048,576 threads
  int row  = idx >> 8;            // 0..4095
  int col  = (idx & 255) << 2;    // 0..1020, 4-aligned (within one head)
  int b    = row >> 11;
  int q    = row & 2047;
  int h    = col >> 6;
  size_t li = (size_t)((b << 4) + h) * SEQL + q;
  float linv = 1.0f / (L0[li] + L1[li] - nmask[b]);
  size_t off = (size_t)row * MD + col;
  float4 a = *(const float4*)(O0 + off);
  float4 c = *(const float4*)(O1 + off);
  ushort4 o;
  o.x = f2bf((a.x + c.x) * linv);
  o.y = f2bf((a.y + c.y) * linv);
  o.z = f2bf((a.z + c.z) * linv);
  o.w = f2bf((a.w + c.w) * linv);
  *(ushort4*)(attn + off) = o;
}

// ---------------- launch ----------------
extern "C" void kernel_launch(void* const* d_in, const int* in_sizes, int n_in,
                              void* d_out, int out_size, void* d_ws, size_t ws_size,
                              hipStream_t stream) {
  const float* in_k = (const float*)d_in[0];
  const float* in_q = (const float*)d_in[1];
  const float* in_v = (const float*)d_in[2];
  const float* mask = (const float*)d_in[3];
  const float* Wq   = (const float*)d_in[4];
  const float* bq   = (const float*)d_in[5];
  const float* Wk   = (const float*)d_in[6];
  const float* bk   = (const float*)d_in[7];
  const float* Wv   = (const float*)d_in[8];
  const float* bv   = (const float*)d_in[9];
  const float* Wo   = (const float*)d_in[10];
  const float* bo   = (const float*)d_in[11];

  const size_t XN = (size_t)MROWS * MD;   // 4,194,304 elems
  const size_t WN = (size_t)MD * MD;      // 1,048,576 elems
  char* w = (char*)d_ws;
  size_t off = 0;
  auto alloc = [&](size_t bytes) { char* p = w + off; off += bytes; return p; };
  bf16_t* xq    = (bf16_t*)alloc(XN * 2);
  bf16_t* xk    = (bf16_t*)alloc(XN * 2);
  bf16_t* xv    = (bf16_t*)alloc(XN * 2);   // xk+xv contiguous 16.8MB -> O0 alias
  bf16_t* wqb   = (bf16_t*)alloc(WN * 2);
  bf16_t* wkb   = (bf16_t*)alloc(WN * 2);
  bf16_t* wvb   = (bf16_t*)alloc(WN * 2);
  bf16_t* wob   = (bf16_t*)alloc(WN * 2);
  bf16_t* Qp    = (bf16_t*)alloc(XN * 2);
  bf16_t* Kfp   = (bf16_t*)alloc(XN * 2 + 8192);   // + pad for prefetch overrun
  bf16_t* Vfp   = (bf16_t*)alloc(XN * 2 + 8192);
  float*  bqs   = (float*)alloc(MD * 4);
  float*  nmask = (float*)alloc(16);
  float*  O1    = (float*)alloc(XN * 4);           // 16.8 MB f32 partial
  float*  L0    = (float*)alloc((size_t)BSZ * NHEAD * SEQL * 4);
  float*  L1    = (float*)alloc((size_t)BSZ * NHEAD * SEQL * 4);
  float*  O0    = (float*)xk;   // alias: xk+xv dead after gemm_qkv (16.8 MB)
  bf16_t* attn  = xq;           // alias: xq dead after gemm_qkv
  (void)ws_size;

  // single consolidated convert (3 X + 4 W + bqs + nmask)
  cvt_all<<<16387, 256, 0, stream>>>(in_q, in_k, in_v, Wq, Wk, Wv, Wo, mask, bq,
                                     (unsigned short*)xq, (unsigned short*)xk, (unsigned short*)xv,
                                     (unsigned short*)wqb, (unsigned short*)wkb,
                                     (unsigned short*)wvb, (unsigned short*)wob, bqs, nmask);

  // fused QKV projection; K/V written in MFMA fragment layouts
  gemm_qkv<<<768, 256, 0, stream>>>(xq, xk, xv, wqb, wkb, wvb, bqs, bk, bv, mask, Qp, Kfp, Vfp);

  // flash attention, kv-split by blocks: 1024 blocks x 4 waves, f32 partials
  attn_kernel<<<1024, 256, 0, stream>>>(Qp, Kfp, Vfp, O0, O1, L0, L1);

  // combine partials -> bf16 attn
  combine_kernel<<<4096, 256, 0, stream>>>(O0, O1, L0, L1, nmask, (unsigned short*)attn);

  // output projection -> fp32 d_out (64x128 tiles, 2 blocks/CU)
  gemm_out64<<<512, 256, 0, stream>>>(attn, wob, bo, (float*)d_out);
}

// Round 22
// 129.075 us; speedup vs baseline: 1.3104x; 1.3104x over previous
//
#include <hip/hip_runtime.h>
#include <hip/hip_bf16.h>
#include <stdint.h>

// Problem dims (fixed)
#define MD    1024      // model dim
#define NHEAD 16
#define HDIM  64
#define BSZ   2
#define SEQL  2048
#define MROWS 4096      // BSZ*SEQL

#define SCL2E 0.18033688011112042f   // (1/sqrt(64)) * log2(e), folded into Wq/bq

typedef __bf16 bf16_t;
typedef __bf16  bf16x8 __attribute__((ext_vector_type(8)));
typedef float   f32x4  __attribute__((ext_vector_type(4)));
typedef float   f32x16 __attribute__((ext_vector_type(16)));

// raw v_exp_f32 via compiler-visible builtin (hazards handled by backend).
#if __has_builtin(__builtin_amdgcn_exp2f)
  #define FEXP2(x) __builtin_amdgcn_exp2f(x)
#else
  #define FEXP2(x) exp2f(x)
#endif

// Async global->LDS, 16B per lane. LDS dest is wave-uniform base (+lane*16 by HW).
__device__ __forceinline__ void gload_lds16(const void* g, void* l) {
  __builtin_amdgcn_global_load_lds((const __attribute__((address_space(1))) void*)g,
                                   (__attribute__((address_space(3))) void*)l,
                                   16, 0, 0);
}

__device__ __forceinline__ unsigned short f2bf(float f) {
  unsigned u = __builtin_bit_cast(unsigned, f);
  u += 0x7fffu + ((u >> 16) & 1u);          // round-to-nearest-even
  return (unsigned short)(u >> 16);
}

// packed 2xf32 -> 2xbf16 in one dword (src0 -> low half)
__device__ __forceinline__ unsigned cvtpk(float a, float b) {
  unsigned r;
  asm("v_cvt_pk_bf16_f32 %0, %1, %2" : "=v"(r) : "v"(a), "v"(b));
  return r;
}

// ---------------- consolidated convert ----------------
// grid 16387: [0,12288) X (4096 each), [12288,16384) W (1024 each; Wq scaled),
// 16384: bq*SCL2E -> bqs ; 16385/16386: nmask[b] = sum(1-mask[b][:])
__global__ __launch_bounds__(256)
void cvt_all(const float* __restrict__ q, const float* __restrict__ k, const float* __restrict__ v,
             const float* __restrict__ wq, const float* __restrict__ wk,
             const float* __restrict__ wv, const float* __restrict__ wo,
             const float* __restrict__ mask, const float* __restrict__ bq,
             unsigned short* __restrict__ xq, unsigned short* __restrict__ xk, unsigned short* __restrict__ xv,
             unsigned short* __restrict__ wqb, unsigned short* __restrict__ wkb,
             unsigned short* __restrict__ wvb, unsigned short* __restrict__ wob,
             float* __restrict__ bqs, float* __restrict__ nmask) {
  int bx = blockIdx.x;
  if (bx >= 16384) {
    if (bx == 16384) {                    // bqs = bq * SCL2E (1024 floats)
      int i = threadIdx.x;
      float4 val = ((const float4*)bq)[i];
      float4 o;
      o.x = val.x * SCL2E; o.y = val.y * SCL2E; o.z = val.z * SCL2E; o.w = val.w * SCL2E;
      ((float4*)bqs)[i] = o;
    } else {                              // nmask[b]
      int b = bx - 16385;
      const float* mp = mask + b * SEQL + threadIdx.x * 8;
      float s = 0.0f;
#pragma unroll
      for (int j = 0; j < 8; ++j) s += 1.0f - mp[j];
      for (int d = 1; d < 64; d <<= 1) s += __shfl_xor(s, d);
      __shared__ float wsum[4];
      if ((threadIdx.x & 63) == 0) wsum[threadIdx.x >> 6] = s;
      __syncthreads();
      if (threadIdx.x == 0) nmask[b] = wsum[0] + wsum[1] + wsum[2] + wsum[3];
    }
    return;
  }
  const float* in; unsigned short* out; int i;
  float scale = 1.0f;
  if (bx < 12288) {
    int t = bx >> 12;
    in  = (t == 0) ? q : (t == 1) ? k : v;
    out = (t == 0) ? xq : (t == 1) ? xk : xv;
    i = (bx & 4095) * 256 + threadIdx.x;
  } else {
    int t = (bx - 12288) >> 10;
    in  = (t == 0) ? wq : (t == 1) ? wk : (t == 2) ? wv : wo;
    out = (t == 0) ? wqb : (t == 1) ? wkb : (t == 2) ? wvb : wob;
    if (t == 0) scale = SCL2E;
    i = (bx & 1023) * 256 + threadIdx.x;
  }
  float4 val = ((const float4*)in)[i];
  ushort4 o;
  o.x = f2bf(val.x * scale); o.y = f2bf(val.y * scale);
  o.z = f2bf(val.z * scale); o.w = f2bf(val.w * scale);
  ((ushort4*)out)[i] = o;
}

// ---------------- GEMM: C[m,n] = sum_k A[m,k]*B[n,k] + bias[n] ----------------
// 128x128 tile, BK=64, 4 waves (2x2 of 64x64), 16x16x32 bf16 MFMA.
// SHARED BUFFER IS PASSED IN (declared once per kernel!).
// MODE: 0 = bf16 row-major [m][n], optional runtime row-mask;
//       1 = f32 row-major;
//       2 = bf16 V in PV(32x32x16) B-frag layout, row-masked;
//       3 = bf16 K in QKt(32x32x16) A-frag layout, row-masked.
template<int MODE>
__device__ __forceinline__ void gemm_body(char* __restrict__ sm,
                                          const bf16_t* __restrict__ A,
                                          const bf16_t* __restrict__ Bm,
                                          const float*  __restrict__ bias,
                                          const float*  __restrict__ mask,
                                          void* __restrict__ Cout, int tile) {
  char* lsA = sm;
  char* lsB = sm + 16384;
  const int tid  = threadIdx.x;
  const int lane = tid & 63;
  const int wv   = tid >> 6;
  const int wm   = wv >> 1, wn = wv & 1;
  const int m0   = (tile >> 3) << 7;   // 32 m-tiles
  const int n0   = (tile & 7)  << 7;   // 8 n-tiles
  const int l15  = lane & 15;
  const int g16  = (lane >> 4) << 4;   // k-group byte base

  f32x4 acc[4][4] = {};

  for (int kk = 0; kk < MD; kk += 64) {
#pragma unroll
    for (int i = 0; i < 4; ++i) {
      int ch  = (wv << 2) + i;
      int o   = ch * 1024 + (lane << 4);
      int row = o >> 7;
      int scb = (o & 127) ^ ((row & 7) << 4);   // pre-swizzled source column byte
      const char* gA = (const char*)A  + (((size_t)(m0 + row) * MD + kk) << 1) + scb;
      const char* gB = (const char*)Bm + (((size_t)(n0 + row) * MD + kk) << 1) + scb;
      gload_lds16(gA, lsA + ch * 1024);
      gload_lds16(gB, lsB + ch * 1024);
    }
    __syncthreads();
#pragma unroll
    for (int s = 0; s < 2; ++s) {
      bf16x8 af[4], bfv[4];
#pragma unroll
      for (int mi = 0; mi < 4; ++mi) {
        int r  = (wm << 6) + (mi << 4) + l15;
        int cb = (g16 + (s << 6)) ^ ((r & 7) << 4);
        af[mi] = *(const bf16x8*)(lsA + (r << 7) + cb);
      }
#pragma unroll
      for (int ni = 0; ni < 4; ++ni) {
        int r  = (wn << 6) + (ni << 4) + l15;
        int cb = (g16 + (s << 6)) ^ ((r & 7) << 4);
        bfv[ni] = *(const bf16x8*)(lsB + (r << 7) + cb);
      }
      __builtin_amdgcn_s_setprio(1);
#pragma unroll
      for (int mi = 0; mi < 4; ++mi)
#pragma unroll
        for (int ni = 0; ni < 4; ++ni)
          acc[mi][ni] = __builtin_amdgcn_mfma_f32_16x16x32_bf16(af[mi], bfv[ni], acc[mi][ni], 0, 0, 0);
      __builtin_amdgcn_s_setprio(0);
    }
    __syncthreads();
  }

  // epilogue: C/D layout col = lane&15, row = (lane>>4)*4 + reg
  float bvv[4];
#pragma unroll
  for (int ni = 0; ni < 4; ++ni) bvv[ni] = bias[n0 + (wn << 6) + (ni << 4) + l15];
#pragma unroll
  for (int mi = 0; mi < 4; ++mi) {
    int m = m0 + (wm << 6) + (mi << 4) + ((lane >> 4) << 2);  // token rows m..m+3
    float4 mk = {1.0f, 1.0f, 1.0f, 1.0f};
    if constexpr (MODE == 2 || MODE == 3) mk = *(const float4*)&mask[m];
    if constexpr (MODE == 0) { if (mask) mk = *(const float4*)&mask[m]; }
#pragma unroll
    for (int ni = 0; ni < 4; ++ni) {
      int col = n0 + (wn << 6) + (ni << 4) + l15;
      if constexpr (MODE == 2) {
        // V PV-B-frag layout; 4 consecutive kv -> 4 contiguous elems (8B store)
        int b2 = m >> 11; int kv = m & 2047;
        int hh = col >> 6; int dd = col & 63;
        int dl = (dd >> 5) & 1; int dcol = dd & 31;
        size_t base = (size_t)((b2 << 4) + hh) * 131072 + (size_t)(kv >> 5) * 2048
                    + (size_t)((((kv >> 4) & 1) << 1) + dl) * 512
                    + (size_t)((((kv >> 3) & 1) << 5) + dcol) * 8 + (kv & 7);
        ushort4 pk;
        pk.x = f2bf((acc[mi][ni][0] + bvv[ni]) * mk.x);
        pk.y = f2bf((acc[mi][ni][1] + bvv[ni]) * mk.y);
        pk.z = f2bf((acc[mi][ni][2] + bvv[ni]) * mk.z);
        pk.w = f2bf((acc[mi][ni][3] + bvv[ni]) * mk.w);
        *(ushort4*)((unsigned short*)Cout + base) = pk;
      } else if constexpr (MODE == 3) {
        // K QKt-A-frag layout; 4 consecutive kv -> stride-8 scalar stores
        int b2 = m >> 11; int kv = m & 2047;
        int hh = col >> 6; int dd = col & 63;
        size_t base = (size_t)((b2 << 4) + hh) * 131072 + (size_t)(kv >> 5) * 2048
                    + (size_t)(dd >> 4) * 512
                    + (size_t)((((dd >> 3) & 1) << 5) + (kv & 31)) * 8 + (dd & 7);
#pragma unroll
        for (int r = 0; r < 4; ++r)
          ((unsigned short*)Cout)[base + ((size_t)r << 3)] =
              f2bf((acc[mi][ni][r] + bvv[ni]) * ((const float*)&mk)[r]);
      } else {
#pragma unroll
        for (int r = 0; r < 4; ++r) {
          float vv = acc[mi][ni][r] + bvv[ni];
          if constexpr (MODE == 0) vv *= ((const float*)&mk)[r];
          if constexpr (MODE == 1) ((float*)Cout)[(size_t)(m + r) * MD + col] = vv;
          else                     ((bf16_t*)Cout)[(size_t)(m + r) * MD + col] = (bf16_t)vv;
        }
      }
    }
  }
}

// fused QKV (768 blocks = 3/CU): Q row-major pre-scaled; K -> Kf frags; V -> Vf frags.
__global__ __launch_bounds__(256, 3)
void gemm_qkv(const bf16_t* __restrict__ xq, const bf16_t* __restrict__ xk, const bf16_t* __restrict__ xv,
              const bf16_t* __restrict__ wq, const bf16_t* __restrict__ wk, const bf16_t* __restrict__ wv_,
              const float* __restrict__ bqs, const float* __restrict__ bk, const float* __restrict__ bv,
              const float* __restrict__ mask,
              bf16_t* __restrict__ Qo, bf16_t* __restrict__ Kfo, bf16_t* __restrict__ Vfo) {
  __shared__ __align__(1024) char sm[32768];
  int t = blockIdx.x & 255;
  int g = blockIdx.x >> 8;
  if (g == 0)      gemm_body<0>(sm, xq, wq,  bqs, nullptr, Qo,  t);
  else if (g == 1) gemm_body<3>(sm, xk, wk,  bk,  mask,    Kfo, t);
  else             gemm_body<2>(sm, xv, wv_, bv,  mask,    Vfo, t);
}

// output projection, 64x128 tiles -> 512 blocks = 2 blocks/CU.
__global__ __launch_bounds__(256, 2)
void gemm_out64(const bf16_t* __restrict__ A, const bf16_t* __restrict__ Bm,
                const float* __restrict__ bias, float* __restrict__ C) {
  __shared__ __align__(1024) char sm[24576];
  char* lsA = sm;           // 64 rows x 128B
  char* lsB = sm + 8192;    // 128 rows x 128B
  const int tile = (int)blockIdx.x;
  const int m0   = (tile >> 3) << 6;   // 64 m-tiles
  const int n0   = (tile & 7)  << 7;   // 8 n-tiles
  const int tid  = threadIdx.x;
  const int lane = tid & 63;
  const int wv   = tid >> 6;
  const int l15  = lane & 15;
  const int g16  = (lane >> 4) << 4;

  f32x4 acc[4][2] = {};

  for (int kk = 0; kk < MD; kk += 64) {
#pragma unroll
    for (int i = 0; i < 6; ++i) {
      int ch = wv * 6 + i;             // 24 chunks: 0-7 A, 8-23 B
      if (ch < 8) {
        int o   = ch * 1024 + (lane << 4);
        int row = o >> 7;
        int scb = (o & 127) ^ ((row & 7) << 4);
        gload_lds16((const char*)A + (((size_t)(m0 + row) * MD + kk) << 1) + scb,
                    lsA + ch * 1024);
      } else {
        int cl  = ch - 8;
        int o   = cl * 1024 + (lane << 4);
        int row = o >> 7;
        int scb = (o & 127) ^ ((row & 7) << 4);
        gload_lds16((const char*)Bm + (((size_t)(n0 + row) * MD + kk) << 1) + scb,
                    lsB + cl * 1024);
      }
    }
    __syncthreads();
#pragma unroll
    for (int s = 0; s < 2; ++s) {
      bf16x8 af[4], bfv[2];
#pragma unroll
      for (int mi = 0; mi < 4; ++mi) {
        int r  = (mi << 4) + l15;
        int cb = (g16 + (s << 6)) ^ ((r & 7) << 4);
        af[mi] = *(const bf16x8*)(lsA + (r << 7) + cb);
      }
#pragma unroll
      for (int ni = 0; ni < 2; ++ni) {
        int r  = (wv << 5) + (ni << 4) + l15;
        int cb = (g16 + (s << 6)) ^ ((r & 7) << 4);
        bfv[ni] = *(const bf16x8*)(lsB + (r << 7) + cb);
      }
      __builtin_amdgcn_s_setprio(1);
#pragma unroll
      for (int mi = 0; mi < 4; ++mi)
#pragma unroll
        for (int ni = 0; ni < 2; ++ni)
          acc[mi][ni] = __builtin_amdgcn_mfma_f32_16x16x32_bf16(af[mi], bfv[ni], acc[mi][ni], 0, 0, 0);
      __builtin_amdgcn_s_setprio(0);
    }
    __syncthreads();
  }

  float bvv[2];
#pragma unroll
  for (int ni = 0; ni < 2; ++ni) bvv[ni] = bias[n0 + (wv << 5) + (ni << 4) + l15];
#pragma unroll
  for (int mi = 0; mi < 4; ++mi) {
    int m = m0 + (mi << 4) + ((lane >> 4) << 2);
#pragma unroll
    for (int ni = 0; ni < 2; ++ni) {
      int col = n0 + (wv << 5) + (ni << 4) + l15;
#pragma unroll
      for (int r = 0; r < 4; ++r)
        C[(size_t)(m + r) * MD + col] = acc[mi][ni][r] + bvv[ni];
    }
  }
}

// ---------------- flash attention: all-fragment 32x32, KV-SPLIT BY BLOCKS ---
// grid 1024 = b(2)*half(2)*h(16)*qtile(16), XCD swizzle; block 256 = 4 waves,
// each wave owns 32 q, sweeps its block's kv-HALF (32 chunks). 4096 waves.
// launch_bounds(256,2): R21's (256,4) made hipcc clamp to the 64-VGPR tier
// and spill ~55MB (WRITE_SIZE 88.5MB, attn 103us). The loose bound lets the
// allocator take ~100-128 VGPRs; residency is set by ACTUAL VGPR use, so at
// <=128 VGPR, 4 blocks/CU still co-schedule -> 4 waves/SIMD, no spill.
// No-max softmax partials additive: blocks write f32 O-partials + l-partials;
// combine kernel finishes (O0+O1)/(l0+l1-nmask).
__global__ __launch_bounds__(256, 2)
void attn_kernel(const bf16_t* __restrict__ Q, const bf16_t* __restrict__ Kf,
                 const bf16_t* __restrict__ Vf,
                 float* __restrict__ O0, float* __restrict__ O1,
                 float* __restrict__ L0, float* __restrict__ L1) {
  int bid = (int)blockIdx.x;
  int lb  = (bid & 7) * 128 + (bid >> 3);   // 1024 = 8 x 128, bijective
  const int tid  = threadIdx.x;
  const int lane = tid & 63;
  const int w    = tid >> 6;
  const int qt   = lb & 15;
  const int h    = (lb >> 4) & 15;
  const int half = (lb >> 8) & 1;
  const int b    = lb >> 9;
  const int q0w  = (qt << 7) + (w << 5);
  const int l31  = lane & 31;
  const int hi   = lane >> 5;

  // Q B-frags: lane holds Q[q=l31][d = s4*16 + hi*8 + j]
  bf16x8 qa[4];
  {
    const bf16_t* qp = Q + (size_t)(b * SEQL + q0w + l31) * MD + h * HDIM + (hi << 3);
#pragma unroll
    for (int s4 = 0; s4 < 4; ++s4) qa[s4] = *(const bf16x8*)(qp + (s4 << 4));
  }

  const bf16_t* KfB = Kf + (size_t)((b << 4) + h) * 131072;
  const bf16_t* VfB = Vf + (size_t)((b << 4) + h) * 131072;
  const int c0 = half << 5;

  f32x16 oacc0 = {};   // d 0-31
  f32x16 oacc1 = {};   // d 32-63
  float lrun = 0.0f;

  bf16x8 kA[4], vA[4], kB[4], vB[4];

  auto LDKV = [&](int c, bf16x8* kf, bf16x8* vf) {
    const bf16_t* kp = KfB + (size_t)c * 2048 + (lane << 3);
    const bf16_t* vp = VfB + (size_t)c * 2048 + (lane << 3);
#pragma unroll
    for (int s4 = 0; s4 < 4; ++s4) kf[s4] = *(const bf16x8*)(kp + (s4 << 9));
#pragma unroll
    for (int u = 0; u < 4; ++u)   vf[u] = *(const bf16x8*)(vp + (u << 9));
  };

  auto BLK = [&](bf16x8* kf, bf16x8* vf) {
    f32x16 sacc = {};
    __builtin_amdgcn_s_setprio(1);
#pragma unroll
    for (int s4 = 0; s4 < 4; ++s4)
      sacc = __builtin_amdgcn_mfma_f32_32x32x16_bf16(kf[s4], qa[s4], sacc, 0, 0, 0);
    __builtin_amdgcn_s_setprio(0);
    float e[16];
#pragma unroll
    for (int r = 0; r < 16; ++r) e[r] = FEXP2(sacc[r]);
    lrun += ((e[0] + e[1]) + (e[2] + e[3])) + ((e[4] + e[5]) + (e[6] + e[7]))
          + ((e[8] + e[9]) + (e[10] + e[11])) + ((e[12] + e[13]) + (e[14] + e[15]));
    // P -> PV A-frags (kv 0-15 and 16-31) via cvt_pk + permlane32_swap
    unsigned x1 = cvtpk(e[0], e[1]),  x2 = cvtpk(e[2], e[3]);
    unsigned y1 = cvtpk(e[4], e[5]),  y2 = cvtpk(e[6], e[7]);
    unsigned z1 = cvtpk(e[8], e[9]),  z2 = cvtpk(e[10], e[11]);
    unsigned w1 = cvtpk(e[12], e[13]), w2 = cvtpk(e[14], e[15]);
    asm("v_permlane32_swap_b32 %0, %1" : "+v"(x1), "+v"(y1));
    asm("v_permlane32_swap_b32 %0, %1" : "+v"(x2), "+v"(y2));
    asm("v_permlane32_swap_b32 %0, %1" : "+v"(z1), "+v"(w1));
    asm("v_permlane32_swap_b32 %0, %1" : "+v"(z2), "+v"(w2));
    union { unsigned u[4]; bf16x8 v; } p0, p1;
    p0.u[0] = x1; p0.u[1] = x2; p0.u[2] = y1; p0.u[3] = y2;
    p1.u[0] = z1; p1.u[1] = z2; p1.u[2] = w1; p1.u[3] = w2;
    __builtin_amdgcn_s_setprio(1);
    oacc0 = __builtin_amdgcn_mfma_f32_32x32x16_bf16(p0.v, vf[0], oacc0, 0, 0, 0);
    oacc1 = __builtin_amdgcn_mfma_f32_32x32x16_bf16(p0.v, vf[1], oacc1, 0, 0, 0);
    oacc0 = __builtin_amdgcn_mfma_f32_32x32x16_bf16(p1.v, vf[2], oacc0, 0, 0, 0);
    oacc1 = __builtin_amdgcn_mfma_f32_32x32x16_bf16(p1.v, vf[3], oacc1, 0, 0, 0);
    __builtin_amdgcn_s_setprio(0);
  };

  LDKV(c0, kA, vA);
  for (int ii = 0; ii < 16; ++ii) {
    LDKV(c0 + (ii << 1) + 1, kB, vB);
    BLK(kA, vA);
    LDKV(c0 + (ii << 1) + 2, kA, vA);   // last prefetch overruns into next
    BLK(kB, vB);                        // half/pad (unused -> harmless)
  }

  // partial epilogue: no normalize; f32 O-partials + per-q l-partials
  lrun += __shfl_xor(lrun, 32);
  float* Op = half ? O1 : O0;
  float* Lp = half ? L1 : L0;
#pragma unroll
  for (int r = 0; r < 16; ++r) {
    int q = (r & 3) + ((r >> 2) << 3) + (hi << 2);
    size_t ro = (size_t)(b * SEQL + q0w + q) * MD + h * HDIM;
    Op[ro + l31]      = oacc0[r];
    Op[ro + 32 + l31] = oacc1[r];
  }
  if (lane < 32) Lp[(size_t)((b << 4) + h) * SEQL + q0w + l31] = lrun;
}

// combine: attn = (O0+O1) / (l0+l1-nmask[b]), f32 -> bf16. 4096 blocks x 256.
__global__ __launch_bounds__(256)
void combine_kernel(const float* __restrict__ O0, const float* __restrict__ O1,
                    const float* __restrict__ L0, const float* __restrict__ L1,
                    const float* __restrict__ nmask, unsigned short* __restrict__ attn) {
  int idx  = (int)blockIdx.x * 256 + threadIdx.x;   // 1,048,576 threads
  int row  = idx >> 8;            // 0..4095
  int col  = (idx & 255) << 2;    // 0..1020, 4-aligned (within one head)
  int b    = row >> 11;
  int q    = row & 2047;
  int h    = col >> 6;
  size_t li = (size_t)((b << 4) + h) * SEQL + q;
  float linv = 1.0f / (L0[li] + L1[li] - nmask[b]);
  size_t off = (size_t)row * MD + col;
  float4 a = *(const float4*)(O0 + off);
  float4 c = *(const float4*)(O1 + off);
  ushort4 o;
  o.x = f2bf((a.x + c.x) * linv);
  o.y = f2bf((a.y + c.y) * linv);
  o.z = f2bf((a.z + c.z) * linv);
  o.w = f2bf((a.w + c.w) * linv);
  *(ushort4*)(attn + off) = o;
}

// ---------------- launch ----------------
extern "C" void kernel_launch(void* const* d_in, const int* in_sizes, int n_in,
                              void* d_out, int out_size, void* d_ws, size_t ws_size,
                              hipStream_t stream) {
  const float* in_k = (const float*)d_in[0];
  const float* in_q = (const float*)d_in[1];
  const float* in_v = (const float*)d_in[2];
  const float* mask = (const float*)d_in[3];
  const float* Wq   = (const float*)d_in[4];
  const float* bq   = (const float*)d_in[5];
  const float* Wk   = (const float*)d_in[6];
  const float* bk   = (const float*)d_in[7];
  const float* Wv   = (const float*)d_in[8];
  const float* bv   = (const float*)d_in[9];
  const float* Wo   = (const float*)d_in[10];
  const float* bo   = (const float*)d_in[11];

  const size_t XN = (size_t)MROWS * MD;   // 4,194,304 elems
  const size_t WN = (size_t)MD * MD;      // 1,048,576 elems
  char* w = (char*)d_ws;
  size_t off = 0;
  auto alloc = [&](size_t bytes) { char* p = w + off; off += bytes; return p; };
  bf16_t* xq    = (bf16_t*)alloc(XN * 2);
  bf16_t* xk    = (bf16_t*)alloc(XN * 2);
  bf16_t* xv    = (bf16_t*)alloc(XN * 2);   // xk+xv contiguous 16.8MB -> O0 alias
  bf16_t* wqb   = (bf16_t*)alloc(WN * 2);
  bf16_t* wkb   = (bf16_t*)alloc(WN * 2);
  bf16_t* wvb   = (bf16_t*)alloc(WN * 2);
  bf16_t* wob   = (bf16_t*)alloc(WN * 2);
  bf16_t* Qp    = (bf16_t*)alloc(XN * 2);
  bf16_t* Kfp   = (bf16_t*)alloc(XN * 2 + 8192);   // + pad for prefetch overrun
  bf16_t* Vfp   = (bf16_t*)alloc(XN * 2 + 8192);
  float*  bqs   = (float*)alloc(MD * 4);
  float*  nmask = (float*)alloc(16);
  float*  O1    = (float*)alloc(XN * 4);           // 16.8 MB f32 partial
  float*  L0    = (float*)alloc((size_t)BSZ * NHEAD * SEQL * 4);
  float*  L1    = (float*)alloc((size_t)BSZ * NHEAD * SEQL * 4);
  float*  O0    = (float*)xk;   // alias: xk+xv dead after gemm_qkv (16.8 MB)
  bf16_t* attn  = xq;           // alias: xq dead after gemm_qkv
  (void)ws_size;

  // single consolidated convert (3 X + 4 W + bqs + nmask)
  cvt_all<<<16387, 256, 0, stream>>>(in_q, in_k, in_v, Wq, Wk, Wv, Wo, mask, bq,
                                     (unsigned short*)xq, (unsigned short*)xk, (unsigned short*)xv,
                                     (unsigned short*)wqb, (unsigned short*)wkb,
                                     (unsigned short*)wvb, (unsigned short*)wob, bqs, nmask);

  // fused QKV projection; K/V written in MFMA fragment layouts
  gemm_qkv<<<768, 256, 0, stream>>>(xq, xk, xv, wqb, wkb, wvb, bqs, bk, bv, mask, Qp, Kfp, Vfp);

  // flash attention, kv-split by blocks: 1024 blocks x 4 waves, f32 partials
  attn_kernel<<<1024, 256, 0, stream>>>(Qp, Kfp, Vfp, O0, O1, L0, L1);

  // combine partials -> bf16 attn
  combine_kernel<<<4096, 256, 0, stream>>>(O0, O1, L0, L1, nmask, (unsigned short*)attn);

  // output projection -> fp32 d_out (64x128 tiles, 2 blocks/CU)
  gemm_out64<<<512, 256, 0, stream>>>(attn, wob, bo, (float*)d_out);
}

// Round 23
// 119.824 us; speedup vs baseline: 1.4116x; 1.0772x over previous
//
#include <hip/hip_runtime.h>
#include <hip/hip_bf16.h>
#include <stdint.h>

// Problem dims (fixed)
#define MD    1024      // model dim
#define NHEAD 16
#define HDIM  64
#define BSZ   2
#define SEQL  2048
#define MROWS 4096      // BSZ*SEQL

#define SCL2E 0.18033688011112042f   // (1/sqrt(64)) * log2(e), folded into Wq/bq

typedef __bf16 bf16_t;
typedef __bf16  bf16x8 __attribute__((ext_vector_type(8)));
typedef float   f32x4  __attribute__((ext_vector_type(4)));
typedef float   f32x16 __attribute__((ext_vector_type(16)));

// raw v_exp_f32 via compiler-visible builtin (hazards handled by backend).
#if __has_builtin(__builtin_amdgcn_exp2f)
  #define FEXP2(x) __builtin_amdgcn_exp2f(x)
#else
  #define FEXP2(x) exp2f(x)
#endif

// Async global->LDS, 16B per lane. LDS dest is wave-uniform base (+lane*16 by HW).
__device__ __forceinline__ void gload_lds16(const void* g, void* l) {
  __builtin_amdgcn_global_load_lds((const __attribute__((address_space(1))) void*)g,
                                   (__attribute__((address_space(3))) void*)l,
                                   16, 0, 0);
}

__device__ __forceinline__ unsigned short f2bf(float f) {
  unsigned u = __builtin_bit_cast(unsigned, f);
  u += 0x7fffu + ((u >> 16) & 1u);          // round-to-nearest-even
  return (unsigned short)(u >> 16);
}

// packed 2xf32 -> 2xbf16 in one dword (src0 -> low half)
__device__ __forceinline__ unsigned cvtpk(float a, float b) {
  unsigned r;
  asm("v_cvt_pk_bf16_f32 %0, %1, %2" : "=v"(r) : "v"(a), "v"(b));
  return r;
}

// ---------------- consolidated convert ----------------
// grid 16387: [0,12288) X (4096 each), [12288,16384) W (1024 each; Wq scaled),
// 16384: bq*SCL2E -> bqs ; 16385/16386: nmask[b] = sum(1-mask[b][:])
__global__ __launch_bounds__(256)
void cvt_all(const float* __restrict__ q, const float* __restrict__ k, const float* __restrict__ v,
             const float* __restrict__ wq, const float* __restrict__ wk,
             const float* __restrict__ wv, const float* __restrict__ wo,
             const float* __restrict__ mask, const float* __restrict__ bq,
             unsigned short* __restrict__ xq, unsigned short* __restrict__ xk, unsigned short* __restrict__ xv,
             unsigned short* __restrict__ wqb, unsigned short* __restrict__ wkb,
             unsigned short* __restrict__ wvb, unsigned short* __restrict__ wob,
             float* __restrict__ bqs, float* __restrict__ nmask) {
  int bx = blockIdx.x;
  if (bx >= 16384) {
    if (bx == 16384) {                    // bqs = bq * SCL2E (1024 floats)
      int i = threadIdx.x;
      float4 val = ((const float4*)bq)[i];
      float4 o;
      o.x = val.x * SCL2E; o.y = val.y * SCL2E; o.z = val.z * SCL2E; o.w = val.w * SCL2E;
      ((float4*)bqs)[i] = o;
    } else {                              // nmask[b]
      int b = bx - 16385;
      const float* mp = mask + b * SEQL + threadIdx.x * 8;
      float s = 0.0f;
#pragma unroll
      for (int j = 0; j < 8; ++j) s += 1.0f - mp[j];
      for (int d = 1; d < 64; d <<= 1) s += __shfl_xor(s, d);
      __shared__ float wsum[4];
      if ((threadIdx.x & 63) == 0) wsum[threadIdx.x >> 6] = s;
      __syncthreads();
      if (threadIdx.x == 0) nmask[b] = wsum[0] + wsum[1] + wsum[2] + wsum[3];
    }
    return;
  }
  const float* in; unsigned short* out; int i;
  float scale = 1.0f;
  if (bx < 12288) {
    int t = bx >> 12;
    in  = (t == 0) ? q : (t == 1) ? k : v;
    out = (t == 0) ? xq : (t == 1) ? xk : xv;
    i = (bx & 4095) * 256 + threadIdx.x;
  } else {
    int t = (bx - 12288) >> 10;
    in  = (t == 0) ? wq : (t == 1) ? wk : (t == 2) ? wv : wo;
    out = (t == 0) ? wqb : (t == 1) ? wkb : (t == 2) ? wvb : wob;
    if (t == 0) scale = SCL2E;
    i = (bx & 1023) * 256 + threadIdx.x;
  }
  float4 val = ((const float4*)in)[i];
  ushort4 o;
  o.x = f2bf(val.x * scale); o.y = f2bf(val.y * scale);
  o.z = f2bf(val.z * scale); o.w = f2bf(val.w * scale);
  ((ushort4*)out)[i] = o;
}

// ---------------- GEMM: C[m,n] = sum_k A[m,k]*B[n,k] + bias[n] ----------------
// 128x128 tile, BK=64, 4 waves (2x2 of 64x64), 16x16x32 bf16 MFMA.
// SHARED BUFFER IS PASSED IN (declared once per kernel!).
// MODE: 0 = bf16 row-major [m][n], optional runtime row-mask;
//       1 = f32 row-major;
//       2 = bf16 V in PV(32x32x16) B-frag layout, row-masked;
//       3 = bf16 K in QKt(32x32x16) A-frag layout, row-masked.
template<int MODE>
__device__ __forceinline__ void gemm_body(char* __restrict__ sm,
                                          const bf16_t* __restrict__ A,
                                          const bf16_t* __restrict__ Bm,
                                          const float*  __restrict__ bias,
                                          const float*  __restrict__ mask,
                                          void* __restrict__ Cout, int tile) {
  char* lsA = sm;
  char* lsB = sm + 16384;
  const int tid  = threadIdx.x;
  const int lane = tid & 63;
  const int wv   = tid >> 6;
  const int wm   = wv >> 1, wn = wv & 1;
  const int m0   = (tile >> 3) << 7;   // 32 m-tiles
  const int n0   = (tile & 7)  << 7;   // 8 n-tiles
  const int l15  = lane & 15;
  const int g16  = (lane >> 4) << 4;   // k-group byte base

  f32x4 acc[4][4] = {};

  for (int kk = 0; kk < MD; kk += 64) {
#pragma unroll
    for (int i = 0; i < 4; ++i) {
      int ch  = (wv << 2) + i;
      int o   = ch * 1024 + (lane << 4);
      int row = o >> 7;
      int scb = (o & 127) ^ ((row & 7) << 4);   // pre-swizzled source column byte
      const char* gA = (const char*)A  + (((size_t)(m0 + row) * MD + kk) << 1) + scb;
      const char* gB = (const char*)Bm + (((size_t)(n0 + row) * MD + kk) << 1) + scb;
      gload_lds16(gA, lsA + ch * 1024);
      gload_lds16(gB, lsB + ch * 1024);
    }
    __syncthreads();
#pragma unroll
    for (int s = 0; s < 2; ++s) {
      bf16x8 af[4], bfv[4];
#pragma unroll
      for (int mi = 0; mi < 4; ++mi) {
        int r  = (wm << 6) + (mi << 4) + l15;
        int cb = (g16 + (s << 6)) ^ ((r & 7) << 4);
        af[mi] = *(const bf16x8*)(lsA + (r << 7) + cb);
      }
#pragma unroll
      for (int ni = 0; ni < 4; ++ni) {
        int r  = (wn << 6) + (ni << 4) + l15;
        int cb = (g16 + (s << 6)) ^ ((r & 7) << 4);
        bfv[ni] = *(const bf16x8*)(lsB + (r << 7) + cb);
      }
      __builtin_amdgcn_s_setprio(1);
#pragma unroll
      for (int mi = 0; mi < 4; ++mi)
#pragma unroll
        for (int ni = 0; ni < 4; ++ni)
          acc[mi][ni] = __builtin_amdgcn_mfma_f32_16x16x32_bf16(af[mi], bfv[ni], acc[mi][ni], 0, 0, 0);
      __builtin_amdgcn_s_setprio(0);
    }
    __syncthreads();
  }

  // epilogue: C/D layout col = lane&15, row = (lane>>4)*4 + reg
  float bvv[4];
#pragma unroll
  for (int ni = 0; ni < 4; ++ni) bvv[ni] = bias[n0 + (wn << 6) + (ni << 4) + l15];
#pragma unroll
  for (int mi = 0; mi < 4; ++mi) {
    int m = m0 + (wm << 6) + (mi << 4) + ((lane >> 4) << 2);  // token rows m..m+3
    float4 mk = {1.0f, 1.0f, 1.0f, 1.0f};
    if constexpr (MODE == 2 || MODE == 3) mk = *(const float4*)&mask[m];
    if constexpr (MODE == 0) { if (mask) mk = *(const float4*)&mask[m]; }
#pragma unroll
    for (int ni = 0; ni < 4; ++ni) {
      int col = n0 + (wn << 6) + (ni << 4) + l15;
      if constexpr (MODE == 2) {
        // V PV-B-frag layout; 4 consecutive kv -> 4 contiguous elems (8B store)
        int b2 = m >> 11; int kv = m & 2047;
        int hh = col >> 6; int dd = col & 63;
        int dl = (dd >> 5) & 1; int dcol = dd & 31;
        size_t base = (size_t)((b2 << 4) + hh) * 131072 + (size_t)(kv >> 5) * 2048
                    + (size_t)((((kv >> 4) & 1) << 1) + dl) * 512
                    + (size_t)((((kv >> 3) & 1) << 5) + dcol) * 8 + (kv & 7);
        ushort4 pk;
        pk.x = f2bf((acc[mi][ni][0] + bvv[ni]) * mk.x);
        pk.y = f2bf((acc[mi][ni][1] + bvv[ni]) * mk.y);
        pk.z = f2bf((acc[mi][ni][2] + bvv[ni]) * mk.z);
        pk.w = f2bf((acc[mi][ni][3] + bvv[ni]) * mk.w);
        *(ushort4*)((unsigned short*)Cout + base) = pk;
      } else if constexpr (MODE == 3) {
        // K QKt-A-frag layout; 4 consecutive kv -> stride-8 scalar stores
        int b2 = m >> 11; int kv = m & 2047;
        int hh = col >> 6; int dd = col & 63;
        size_t base = (size_t)((b2 << 4) + hh) * 131072 + (size_t)(kv >> 5) * 2048
                    + (size_t)(dd >> 4) * 512
                    + (size_t)((((dd >> 3) & 1) << 5) + (kv & 31)) * 8 + (dd & 7);
#pragma unroll
        for (int r = 0; r < 4; ++r)
          ((unsigned short*)Cout)[base + ((size_t)r << 3)] =
              f2bf((acc[mi][ni][r] + bvv[ni]) * ((const float*)&mk)[r]);
      } else {
#pragma unroll
        for (int r = 0; r < 4; ++r) {
          float vv = acc[mi][ni][r] + bvv[ni];
          if constexpr (MODE == 0) vv *= ((const float*)&mk)[r];
          if constexpr (MODE == 1) ((float*)Cout)[(size_t)(m + r) * MD + col] = vv;
          else                     ((bf16_t*)Cout)[(size_t)(m + r) * MD + col] = (bf16_t)vv;
        }
      }
    }
  }
}

// fused QKV (768 blocks = 3/CU): Q row-major pre-scaled; K -> Kf frags; V -> Vf frags.
__global__ __launch_bounds__(256, 3)
void gemm_qkv(const bf16_t* __restrict__ xq, const bf16_t* __restrict__ xk, const bf16_t* __restrict__ xv,
              const bf16_t* __restrict__ wq, const bf16_t* __restrict__ wk, const bf16_t* __restrict__ wv_,
              const float* __restrict__ bqs, const float* __restrict__ bk, const float* __restrict__ bv,
              const float* __restrict__ mask,
              bf16_t* __restrict__ Qo, bf16_t* __restrict__ Kfo, bf16_t* __restrict__ Vfo) {
  __shared__ __align__(1024) char sm[32768];
  int t = blockIdx.x & 255;
  int g = blockIdx.x >> 8;
  if (g == 0)      gemm_body<0>(sm, xq, wq,  bqs, nullptr, Qo,  t);
  else if (g == 1) gemm_body<3>(sm, xk, wk,  bk,  mask,    Kfo, t);
  else             gemm_body<2>(sm, xv, wv_, bv,  mask,    Vfo, t);
}

// output projection, 64x128 tiles -> 512 blocks = 2 blocks/CU.
__global__ __launch_bounds__(256, 2)
void gemm_out64(const bf16_t* __restrict__ A, const bf16_t* __restrict__ Bm,
                const float* __restrict__ bias, float* __restrict__ C) {
  __shared__ __align__(1024) char sm[24576];
  char* lsA = sm;           // 64 rows x 128B
  char* lsB = sm + 8192;    // 128 rows x 128B
  const int tile = (int)blockIdx.x;
  const int m0   = (tile >> 3) << 6;   // 64 m-tiles
  const int n0   = (tile & 7)  << 7;   // 8 n-tiles
  const int tid  = threadIdx.x;
  const int lane = tid & 63;
  const int wv   = tid >> 6;
  const int l15  = lane & 15;
  const int g16  = (lane >> 4) << 4;

  f32x4 acc[4][2] = {};

  for (int kk = 0; kk < MD; kk += 64) {
#pragma unroll
    for (int i = 0; i < 6; ++i) {
      int ch = wv * 6 + i;             // 24 chunks: 0-7 A, 8-23 B
      if (ch < 8) {
        int o   = ch * 1024 + (lane << 4);
        int row = o >> 7;
        int scb = (o & 127) ^ ((row & 7) << 4);
        gload_lds16((const char*)A + (((size_t)(m0 + row) * MD + kk) << 1) + scb,
                    lsA + ch * 1024);
      } else {
        int cl  = ch - 8;
        int o   = cl * 1024 + (lane << 4);
        int row = o >> 7;
        int scb = (o & 127) ^ ((row & 7) << 4);
        gload_lds16((const char*)Bm + (((size_t)(n0 + row) * MD + kk) << 1) + scb,
                    lsB + cl * 1024);
      }
    }
    __syncthreads();
#pragma unroll
    for (int s = 0; s < 2; ++s) {
      bf16x8 af[4], bfv[2];
#pragma unroll
      for (int mi = 0; mi < 4; ++mi) {
        int r  = (mi << 4) + l15;
        int cb = (g16 + (s << 6)) ^ ((r & 7) << 4);
        af[mi] = *(const bf16x8*)(lsA + (r << 7) + cb);
      }
#pragma unroll
      for (int ni = 0; ni < 2; ++ni) {
        int r  = (wv << 5) + (ni << 4) + l15;
        int cb = (g16 + (s << 6)) ^ ((r & 7) << 4);
        bfv[ni] = *(const bf16x8*)(lsB + (r << 7) + cb);
      }
      __builtin_amdgcn_s_setprio(1);
#pragma unroll
      for (int mi = 0; mi < 4; ++mi)
#pragma unroll
        for (int ni = 0; ni < 2; ++ni)
          acc[mi][ni] = __builtin_amdgcn_mfma_f32_16x16x32_bf16(af[mi], bfv[ni], acc[mi][ni], 0, 0, 0);
      __builtin_amdgcn_s_setprio(0);
    }
    __syncthreads();
  }

  float bvv[2];
#pragma unroll
  for (int ni = 0; ni < 2; ++ni) bvv[ni] = bias[n0 + (wv << 5) + (ni << 4) + l15];
#pragma unroll
  for (int mi = 0; mi < 4; ++mi) {
    int m = m0 + (mi << 4) + ((lane >> 4) << 2);
#pragma unroll
    for (int ni = 0; ni < 2; ++ni) {
      int col = n0 + (wv << 5) + (ni << 4) + l15;
#pragma unroll
      for (int r = 0; r < 4; ++r)
        C[(size_t)(m + r) * MD + col] = acc[mi][ni][r] + bvv[ni];
    }
  }
}

// ---------------- flash attention: all-fragment 32x32, 64 q per wave --------
// R22 showed attn is L1-BW-bound (~4MB/CU of Kf/Vf register-fill; TLP x2 and
// ILP restructures all flat at ~48-52us). Fix: double reuse per K/V load —
// each wave computes TWO 32-q tiles sharing every kf/vf fragment -> L1 bytes
// per CU halve. grid 256 = b(2)*h(16)*qtile(8 of 256q), XCD swizzle (8x32);
// block 256 = 4 waves x 64 q. 1024 waves total (1/SIMD, grid-limited): the
// two independent q-streams provide intra-wave ILP instead of TLP.
// launch_bounds(256,1): allocator free (~240 VGPR est), only 1 wave/SIMD
// needed resident so high VGPR is harmless; spill only if >512.
__global__ __launch_bounds__(256, 1)
void attn_kernel(const bf16_t* __restrict__ Q, const bf16_t* __restrict__ Kf,
                 const bf16_t* __restrict__ Vf, const float* __restrict__ nmask,
                 bf16_t* __restrict__ O) {
  int bid = (int)blockIdx.x;
  int lb  = (bid & 7) * 32 + (bid >> 3);   // 256 = 8 x 32, bijective
  const int tid  = threadIdx.x;
  const int lane = tid & 63;
  const int w    = tid >> 6;
  const int qt   = lb & 7;
  const int h    = (lb >> 3) & 15;
  const int b    = lb >> 7;
  const int q0w  = (qt << 8) + (w << 6);   // wave owns 64 q: tiles q0w, q0w+32
  const int l31  = lane & 31;
  const int hi   = lane >> 5;

  // Q B-frags for both tiles: lane holds Q[q=l31][d = s4*16 + hi*8 + j]
  bf16x8 qa0[4], qa1[4];
  {
    const bf16_t* qp0 = Q + (size_t)(b * SEQL + q0w + l31) * MD + h * HDIM + (hi << 3);
    const bf16_t* qp1 = qp0 + (size_t)32 * MD;
#pragma unroll
    for (int s4 = 0; s4 < 4; ++s4) { qa0[s4] = *(const bf16x8*)(qp0 + (s4 << 4));
                                     qa1[s4] = *(const bf16x8*)(qp1 + (s4 << 4)); }
  }

  const bf16_t* KfB = Kf + (size_t)((b << 4) + h) * 131072;
  const bf16_t* VfB = Vf + (size_t)((b << 4) + h) * 131072;

  f32x16 o00 = {}, o01 = {};   // tile0: d 0-31, d 32-63
  f32x16 o10 = {}, o11 = {};   // tile1
  float lr0 = 0.0f, lr1 = 0.0f;

  bf16x8 kA[4], vA[4], kB[4], vB[4];

  auto LDKV = [&](int c, bf16x8* kf, bf16x8* vf) {
    const bf16_t* kp = KfB + (size_t)c * 2048 + (lane << 3);
    const bf16_t* vp = VfB + (size_t)c * 2048 + (lane << 3);
#pragma unroll
    for (int s4 = 0; s4 < 4; ++s4) kf[s4] = *(const bf16x8*)(kp + (s4 << 9));
#pragma unroll
    for (int u = 0; u < 4; ++u)   vf[u] = *(const bf16x8*)(vp + (u << 9));
  };

  // softmax + pack one tile's sacc -> PV A-frags; accumulates lr
  auto SMPK = [&](f32x16& sacc, float& lr, bf16x8& pv0, bf16x8& pv1) {
    float e[16];
#pragma unroll
    for (int r = 0; r < 16; ++r) e[r] = FEXP2(sacc[r]);
    lr += ((e[0] + e[1]) + (e[2] + e[3])) + ((e[4] + e[5]) + (e[6] + e[7]))
        + ((e[8] + e[9]) + (e[10] + e[11])) + ((e[12] + e[13]) + (e[14] + e[15]));
    unsigned x1 = cvtpk(e[0], e[1]),  x2 = cvtpk(e[2], e[3]);
    unsigned y1 = cvtpk(e[4], e[5]),  y2 = cvtpk(e[6], e[7]);
    unsigned z1 = cvtpk(e[8], e[9]),  z2 = cvtpk(e[10], e[11]);
    unsigned w1 = cvtpk(e[12], e[13]), w2 = cvtpk(e[14], e[15]);
    asm("v_permlane32_swap_b32 %0, %1" : "+v"(x1), "+v"(y1));
    asm("v_permlane32_swap_b32 %0, %1" : "+v"(x2), "+v"(y2));
    asm("v_permlane32_swap_b32 %0, %1" : "+v"(z1), "+v"(w1));
    asm("v_permlane32_swap_b32 %0, %1" : "+v"(z2), "+v"(w2));
    union { unsigned u[4]; bf16x8 v; } p0, p1;
    p0.u[0] = x1; p0.u[1] = x2; p0.u[2] = y1; p0.u[3] = y2;
    p1.u[0] = z1; p1.u[1] = z2; p1.u[2] = w1; p1.u[3] = w2;
    pv0 = p0.v; pv1 = p1.v;
  };

  // one chunk for BOTH q-tiles (kf/vf shared -> 2x reuse per L1 byte)
  auto BLK = [&](bf16x8* kf, bf16x8* vf) {
    f32x16 s0 = {}, s1 = {};
    __builtin_amdgcn_s_setprio(1);
#pragma unroll
    for (int s4 = 0; s4 < 4; ++s4)
      s0 = __builtin_amdgcn_mfma_f32_32x32x16_bf16(kf[s4], qa0[s4], s0, 0, 0, 0);
#pragma unroll
    for (int s4 = 0; s4 < 4; ++s4)
      s1 = __builtin_amdgcn_mfma_f32_32x32x16_bf16(kf[s4], qa1[s4], s1, 0, 0, 0);
    __builtin_amdgcn_s_setprio(0);
    bf16x8 pA0, pA1, pB0, pB1;
    SMPK(s0, lr0, pA0, pA1);
    __builtin_amdgcn_s_setprio(1);
    o00 = __builtin_amdgcn_mfma_f32_32x32x16_bf16(pA0, vf[0], o00, 0, 0, 0);
    o01 = __builtin_amdgcn_mfma_f32_32x32x16_bf16(pA0, vf[1], o01, 0, 0, 0);
    o00 = __builtin_amdgcn_mfma_f32_32x32x16_bf16(pA1, vf[2], o00, 0, 0, 0);
    o01 = __builtin_amdgcn_mfma_f32_32x32x16_bf16(pA1, vf[3], o01, 0, 0, 0);
    __builtin_amdgcn_s_setprio(0);
    SMPK(s1, lr1, pB0, pB1);
    __builtin_amdgcn_s_setprio(1);
    o10 = __builtin_amdgcn_mfma_f32_32x32x16_bf16(pB0, vf[0], o10, 0, 0, 0);
    o11 = __builtin_amdgcn_mfma_f32_32x32x16_bf16(pB0, vf[1], o11, 0, 0, 0);
    o10 = __builtin_amdgcn_mfma_f32_32x32x16_bf16(pB1, vf[2], o10, 0, 0, 0);
    o11 = __builtin_amdgcn_mfma_f32_32x32x16_bf16(pB1, vf[3], o11, 0, 0, 0);
    __builtin_amdgcn_s_setprio(0);
  };

  LDKV(0, kA, vA);
  for (int ii = 0; ii < 32; ++ii) {
    LDKV((ii << 1) + 1, kB, vB);
    BLK(kA, vA);
    LDKV((ii << 1) + 2, kA, vA);   // ii=31 reads pad block 64 (harmless)
    BLK(kB, vB);
  }

  // epilogue: combine hi halves, normalize, store both tiles (row-major bf16)
  lr0 += __shfl_xor(lr0, 32);
  lr1 += __shfl_xor(lr1, 32);
  const float nm = nmask[b];
  float li0 = 1.0f / (lr0 - nm);
  float li1 = 1.0f / (lr1 - nm);
#pragma unroll
  for (int r = 0; r < 16; ++r) {
    int q = (r & 3) + ((r >> 2) << 3) + (hi << 2);
    size_t ro0 = (size_t)(b * SEQL + q0w + q) * MD + h * HDIM;
    size_t ro1 = ro0 + (size_t)32 * MD;
    float a0 = __shfl(li0, q);
    float a1 = __shfl(li1, q);
    O[ro0 + l31]      = (bf16_t)(o00[r] * a0);
    O[ro0 + 32 + l31] = (bf16_t)(o01[r] * a0);
    O[ro1 + l31]      = (bf16_t)(o10[r] * a1);
    O[ro1 + 32 + l31] = (bf16_t)(o11[r] * a1);
  }
}

// ---------------- launch ----------------
extern "C" void kernel_launch(void* const* d_in, const int* in_sizes, int n_in,
                              void* d_out, int out_size, void* d_ws, size_t ws_size,
                              hipStream_t stream) {
  const float* in_k = (const float*)d_in[0];
  const float* in_q = (const float*)d_in[1];
  const float* in_v = (const float*)d_in[2];
  const float* mask = (const float*)d_in[3];
  const float* Wq   = (const float*)d_in[4];
  const float* bq   = (const float*)d_in[5];
  const float* Wk   = (const float*)d_in[6];
  const float* bk   = (const float*)d_in[7];
  const float* Wv   = (const float*)d_in[8];
  const float* bv   = (const float*)d_in[9];
  const float* Wo   = (const float*)d_in[10];
  const float* bo   = (const float*)d_in[11];

  const size_t XN = (size_t)MROWS * MD;   // 4,194,304 elems
  const size_t WN = (size_t)MD * MD;      // 1,048,576 elems
  char* w = (char*)d_ws;
  size_t off = 0;
  auto alloc = [&](size_t bytes) { char* p = w + off; off += bytes; return p; };
  bf16_t* xq    = (bf16_t*)alloc(XN * 2);
  bf16_t* xk    = (bf16_t*)alloc(XN * 2);
  bf16_t* xv    = (bf16_t*)alloc(XN * 2);
  bf16_t* wqb   = (bf16_t*)alloc(WN * 2);
  bf16_t* wkb   = (bf16_t*)alloc(WN * 2);
  bf16_t* wvb   = (bf16_t*)alloc(WN * 2);
  bf16_t* wob   = (bf16_t*)alloc(WN * 2);
  bf16_t* Qp    = (bf16_t*)alloc(XN * 2);
  bf16_t* Kfp   = (bf16_t*)alloc(XN * 2 + 8192);   // + pad for prefetch overrun
  bf16_t* Vfp   = (bf16_t*)alloc(XN * 2 + 8192);
  float*  bqs   = (float*)alloc(MD * 4);
  float*  nmask = (float*)alloc(16);
  bf16_t* attn  = xq;  // alias: xq is dead after gemm_qkv
  (void)ws_size;

  // single consolidated convert (3 X + 4 W + bqs + nmask)
  cvt_all<<<16387, 256, 0, stream>>>(in_q, in_k, in_v, Wq, Wk, Wv, Wo, mask, bq,
                                     (unsigned short*)xq, (unsigned short*)xk, (unsigned short*)xv,
                                     (unsigned short*)wqb, (unsigned short*)wkb,
                                     (unsigned short*)wvb, (unsigned short*)wob, bqs, nmask);

  // fused QKV projection; K/V written in MFMA fragment layouts
  gemm_qkv<<<768, 256, 0, stream>>>(xq, xk, xv, wqb, wkb, wvb, bqs, bk, bv, mask, Qp, Kfp, Vfp);

  // flash attention: 256 blocks x 4 waves x 64 q (2x K/V reuse per load)
  attn_kernel<<<256, 256, 0, stream>>>(Qp, Kfp, Vfp, nmask, attn);

  // output projection -> fp32 d_out (64x128 tiles, 2 blocks/CU)
  gemm_out64<<<512, 256, 0, stream>>>(attn, wob, bo, (float*)d_out);
}

// Round 24
// 118.389 us; speedup vs baseline: 1.4287x; 1.0121x over previous
//
#include <hip/hip_runtime.h>
#include <hip/hip_bf16.h>
#include <stdint.h>

// Problem dims (fixed)
#define MD    1024      // model dim
#define NHEAD 16
#define HDIM  64
#define BSZ   2
#define SEQL  2048
#define MROWS 4096      // BSZ*SEQL

#define SCL2E 0.18033688011112042f   // (1/sqrt(64)) * log2(e), folded into Wq/bq

typedef __bf16 bf16_t;
typedef __bf16  bf16x8 __attribute__((ext_vector_type(8)));
typedef float   f32x4  __attribute__((ext_vector_type(4)));
typedef float   f32x16 __attribute__((ext_vector_type(16)));

// raw v_exp_f32 via compiler-visible builtin (hazards handled by backend).
#if __has_builtin(__builtin_amdgcn_exp2f)
  #define FEXP2(x) __builtin_amdgcn_exp2f(x)
#else
  #define FEXP2(x) exp2f(x)
#endif

// Async global->LDS, 16B per lane. LDS dest is wave-uniform base (+lane*16 by HW).
__device__ __forceinline__ void gload_lds16(const void* g, void* l) {
  __builtin_amdgcn_global_load_lds((const __attribute__((address_space(1))) void*)g,
                                   (__attribute__((address_space(3))) void*)l,
                                   16, 0, 0);
}

__device__ __forceinline__ unsigned short f2bf(float f) {
  unsigned u = __builtin_bit_cast(unsigned, f);
  u += 0x7fffu + ((u >> 16) & 1u);          // round-to-nearest-even
  return (unsigned short)(u >> 16);
}

// packed 2xf32 -> 2xbf16 in one dword (src0 -> low half)
__device__ __forceinline__ unsigned cvtpk(float a, float b) {
  unsigned r;
  asm("v_cvt_pk_bf16_f32 %0, %1, %2" : "=v"(r) : "v"(a), "v"(b));
  return r;
}

// ---------------- consolidated convert ----------------
// grid 16387: [0,12288) X (4096 each), [12288,16384) W (1024 each; Wq scaled),
// 16384: bq*SCL2E -> bqs ; 16385/16386: nmask[b] = sum(1-mask[b][:])
__global__ __launch_bounds__(256)
void cvt_all(const float* __restrict__ q, const float* __restrict__ k, const float* __restrict__ v,
             const float* __restrict__ wq, const float* __restrict__ wk,
             const float* __restrict__ wv, const float* __restrict__ wo,
             const float* __restrict__ mask, const float* __restrict__ bq,
             unsigned short* __restrict__ xq, unsigned short* __restrict__ xk, unsigned short* __restrict__ xv,
             unsigned short* __restrict__ wqb, unsigned short* __restrict__ wkb,
             unsigned short* __restrict__ wvb, unsigned short* __restrict__ wob,
             float* __restrict__ bqs, float* __restrict__ nmask) {
  int bx = blockIdx.x;
  if (bx >= 16384) {
    if (bx == 16384) {                    // bqs = bq * SCL2E (1024 floats)
      int i = threadIdx.x;
      float4 val = ((const float4*)bq)[i];
      float4 o;
      o.x = val.x * SCL2E; o.y = val.y * SCL2E; o.z = val.z * SCL2E; o.w = val.w * SCL2E;
      ((float4*)bqs)[i] = o;
    } else {                              // nmask[b]
      int b = bx - 16385;
      const float* mp = mask + b * SEQL + threadIdx.x * 8;
      float s = 0.0f;
#pragma unroll
      for (int j = 0; j < 8; ++j) s += 1.0f - mp[j];
      for (int d = 1; d < 64; d <<= 1) s += __shfl_xor(s, d);
      __shared__ float wsum[4];
      if ((threadIdx.x & 63) == 0) wsum[threadIdx.x >> 6] = s;
      __syncthreads();
      if (threadIdx.x == 0) nmask[b] = wsum[0] + wsum[1] + wsum[2] + wsum[3];
    }
    return;
  }
  const float* in; unsigned short* out; int i;
  float scale = 1.0f;
  if (bx < 12288) {
    int t = bx >> 12;
    in  = (t == 0) ? q : (t == 1) ? k : v;
    out = (t == 0) ? xq : (t == 1) ? xk : xv;
    i = (bx & 4095) * 256 + threadIdx.x;
  } else {
    int t = (bx - 12288) >> 10;
    in  = (t == 0) ? wq : (t == 1) ? wk : (t == 2) ? wv : wo;
    out = (t == 0) ? wqb : (t == 1) ? wkb : (t == 2) ? wvb : wob;
    if (t == 0) scale = SCL2E;
    i = (bx & 1023) * 256 + threadIdx.x;
  }
  float4 val = ((const float4*)in)[i];
  ushort4 o;
  o.x = f2bf(val.x * scale); o.y = f2bf(val.y * scale);
  o.z = f2bf(val.z * scale); o.w = f2bf(val.w * scale);
  ((ushort4*)out)[i] = o;
}

// ---------------- GEMM: C[m,n] = sum_k A[m,k]*B[n,k] + bias[n] ----------------
// 128x128 tile, BK=64, 4 waves (2x2 of 64x64), 16x16x32 bf16 MFMA.
// SHARED BUFFER IS PASSED IN (declared once per kernel!).
// MODE: 0 = bf16 row-major [m][n], optional runtime row-mask;
//       1 = f32 row-major;
//       2 = bf16 V in PV(32x32x16) B-frag layout, row-masked;
//       3 = bf16 K in QKt(32x32x16) A-frag layout, row-masked.
template<int MODE>
__device__ __forceinline__ void gemm_body(char* __restrict__ sm,
                                          const bf16_t* __restrict__ A,
                                          const bf16_t* __restrict__ Bm,
                                          const float*  __restrict__ bias,
                                          const float*  __restrict__ mask,
                                          void* __restrict__ Cout, int tile) {
  char* lsA = sm;
  char* lsB = sm + 16384;
  const int tid  = threadIdx.x;
  const int lane = tid & 63;
  const int wv   = tid >> 6;
  const int wm   = wv >> 1, wn = wv & 1;
  const int m0   = (tile >> 3) << 7;   // 32 m-tiles
  const int n0   = (tile & 7)  << 7;   // 8 n-tiles
  const int l15  = lane & 15;
  const int g16  = (lane >> 4) << 4;   // k-group byte base

  f32x4 acc[4][4] = {};

  for (int kk = 0; kk < MD; kk += 64) {
#pragma unroll
    for (int i = 0; i < 4; ++i) {
      int ch  = (wv << 2) + i;
      int o   = ch * 1024 + (lane << 4);
      int row = o >> 7;
      int scb = (o & 127) ^ ((row & 7) << 4);   // pre-swizzled source column byte
      const char* gA = (const char*)A  + (((size_t)(m0 + row) * MD + kk) << 1) + scb;
      const char* gB = (const char*)Bm + (((size_t)(n0 + row) * MD + kk) << 1) + scb;
      gload_lds16(gA, lsA + ch * 1024);
      gload_lds16(gB, lsB + ch * 1024);
    }
    __syncthreads();
#pragma unroll
    for (int s = 0; s < 2; ++s) {
      bf16x8 af[4], bfv[4];
#pragma unroll
      for (int mi = 0; mi < 4; ++mi) {
        int r  = (wm << 6) + (mi << 4) + l15;
        int cb = (g16 + (s << 6)) ^ ((r & 7) << 4);
        af[mi] = *(const bf16x8*)(lsA + (r << 7) + cb);
      }
#pragma unroll
      for (int ni = 0; ni < 4; ++ni) {
        int r  = (wn << 6) + (ni << 4) + l15;
        int cb = (g16 + (s << 6)) ^ ((r & 7) << 4);
        bfv[ni] = *(const bf16x8*)(lsB + (r << 7) + cb);
      }
      __builtin_amdgcn_s_setprio(1);
#pragma unroll
      for (int mi = 0; mi < 4; ++mi)
#pragma unroll
        for (int ni = 0; ni < 4; ++ni)
          acc[mi][ni] = __builtin_amdgcn_mfma_f32_16x16x32_bf16(af[mi], bfv[ni], acc[mi][ni], 0, 0, 0);
      __builtin_amdgcn_s_setprio(0);
    }
    __syncthreads();
  }

  // epilogue: C/D layout col = lane&15, row = (lane>>4)*4 + reg
  float bvv[4];
#pragma unroll
  for (int ni = 0; ni < 4; ++ni) bvv[ni] = bias[n0 + (wn << 6) + (ni << 4) + l15];
#pragma unroll
  for (int mi = 0; mi < 4; ++mi) {
    int m = m0 + (wm << 6) + (mi << 4) + ((lane >> 4) << 2);  // token rows m..m+3
    float4 mk = {1.0f, 1.0f, 1.0f, 1.0f};
    if constexpr (MODE == 2 || MODE == 3) mk = *(const float4*)&mask[m];
    if constexpr (MODE == 0) { if (mask) mk = *(const float4*)&mask[m]; }
#pragma unroll
    for (int ni = 0; ni < 4; ++ni) {
      int col = n0 + (wn << 6) + (ni << 4) + l15;
      if constexpr (MODE == 2) {
        // V PV-B-frag layout; 4 consecutive kv -> 4 contiguous elems (8B store)
        int b2 = m >> 11; int kv = m & 2047;
        int hh = col >> 6; int dd = col & 63;
        int dl = (dd >> 5) & 1; int dcol = dd & 31;
        size_t base = (size_t)((b2 << 4) + hh) * 131072 + (size_t)(kv >> 5) * 2048
                    + (size_t)((((kv >> 4) & 1) << 1) + dl) * 512
                    + (size_t)((((kv >> 3) & 1) << 5) + dcol) * 8 + (kv & 7);
        ushort4 pk;
        pk.x = f2bf((acc[mi][ni][0] + bvv[ni]) * mk.x);
        pk.y = f2bf((acc[mi][ni][1] + bvv[ni]) * mk.y);
        pk.z = f2bf((acc[mi][ni][2] + bvv[ni]) * mk.z);
        pk.w = f2bf((acc[mi][ni][3] + bvv[ni]) * mk.w);
        *(ushort4*)((unsigned short*)Cout + base) = pk;
      } else if constexpr (MODE == 3) {
        // K QKt-A-frag layout; 4 consecutive kv -> stride-8 scalar stores
        int b2 = m >> 11; int kv = m & 2047;
        int hh = col >> 6; int dd = col & 63;
        size_t base = (size_t)((b2 << 4) + hh) * 131072 + (size_t)(kv >> 5) * 2048
                    + (size_t)(dd >> 4) * 512
                    + (size_t)((((dd >> 3) & 1) << 5) + (kv & 31)) * 8 + (dd & 7);
#pragma unroll
        for (int r = 0; r < 4; ++r)
          ((unsigned short*)Cout)[base + ((size_t)r << 3)] =
              f2bf((acc[mi][ni][r] + bvv[ni]) * ((const float*)&mk)[r]);
      } else {
#pragma unroll
        for (int r = 0; r < 4; ++r) {
          float vv = acc[mi][ni][r] + bvv[ni];
          if constexpr (MODE == 0) vv *= ((const float*)&mk)[r];
          if constexpr (MODE == 1) ((float*)Cout)[(size_t)(m + r) * MD + col] = vv;
          else                     ((bf16_t*)Cout)[(size_t)(m + r) * MD + col] = (bf16_t)vv;
        }
      }
    }
  }
}

// fused QKV (768 blocks = 3/CU): Q row-major pre-scaled; K -> Kf frags; V -> Vf frags.
__global__ __launch_bounds__(256, 3)
void gemm_qkv(const bf16_t* __restrict__ xq, const bf16_t* __restrict__ xk, const bf16_t* __restrict__ xv,
              const bf16_t* __restrict__ wq, const bf16_t* __restrict__ wk, const bf16_t* __restrict__ wv_,
              const float* __restrict__ bqs, const float* __restrict__ bk, const float* __restrict__ bv,
              const float* __restrict__ mask,
              bf16_t* __restrict__ Qo, bf16_t* __restrict__ Kfo, bf16_t* __restrict__ Vfo) {
  __shared__ __align__(1024) char sm[32768];
  int t = blockIdx.x & 255;
  int g = blockIdx.x >> 8;
  if (g == 0)      gemm_body<0>(sm, xq, wq,  bqs, nullptr, Qo,  t);
  else if (g == 1) gemm_body<3>(sm, xk, wk,  bk,  mask,    Kfo, t);
  else             gemm_body<2>(sm, xv, wv_, bv,  mask,    Vfo, t);
}

// output projection, 64x128 tiles -> 512 blocks = 2 blocks/CU.
__global__ __launch_bounds__(256, 2)
void gemm_out64(const bf16_t* __restrict__ A, const bf16_t* __restrict__ Bm,
                const float* __restrict__ bias, float* __restrict__ C) {
  __shared__ __align__(1024) char sm[24576];
  char* lsA = sm;           // 64 rows x 128B
  char* lsB = sm + 8192;    // 128 rows x 128B
  const int tile = (int)blockIdx.x;
  const int m0   = (tile >> 3) << 6;   // 64 m-tiles
  const int n0   = (tile & 7)  << 7;   // 8 n-tiles
  const int tid  = threadIdx.x;
  const int lane = tid & 63;
  const int wv   = tid >> 6;
  const int l15  = lane & 15;
  const int g16  = (lane >> 4) << 4;

  f32x4 acc[4][2] = {};

  for (int kk = 0; kk < MD; kk += 64) {
#pragma unroll
    for (int i = 0; i < 6; ++i) {
      int ch = wv * 6 + i;             // 24 chunks: 0-7 A, 8-23 B
      if (ch < 8) {
        int o   = ch * 1024 + (lane << 4);
        int row = o >> 7;
        int scb = (o & 127) ^ ((row & 7) << 4);
        gload_lds16((const char*)A + (((size_t)(m0 + row) * MD + kk) << 1) + scb,
                    lsA + ch * 1024);
      } else {
        int cl  = ch - 8;
        int o   = cl * 1024 + (lane << 4);
        int row = o >> 7;
        int scb = (o & 127) ^ ((row & 7) << 4);
        gload_lds16((const char*)Bm + (((size_t)(n0 + row) * MD + kk) << 1) + scb,
                    lsB + cl * 1024);
      }
    }
    __syncthreads();
#pragma unroll
    for (int s = 0; s < 2; ++s) {
      bf16x8 af[4], bfv[2];
#pragma unroll
      for (int mi = 0; mi < 4; ++mi) {
        int r  = (mi << 4) + l15;
        int cb = (g16 + (s << 6)) ^ ((r & 7) << 4);
        af[mi] = *(const bf16x8*)(lsA + (r << 7) + cb);
      }
#pragma unroll
      for (int ni = 0; ni < 2; ++ni) {
        int r  = (wv << 5) + (ni << 4) + l15;
        int cb = (g16 + (s << 6)) ^ ((r & 7) << 4);
        bfv[ni] = *(const bf16x8*)(lsB + (r << 7) + cb);
      }
      __builtin_amdgcn_s_setprio(1);
#pragma unroll
      for (int mi = 0; mi < 4; ++mi)
#pragma unroll
        for (int ni = 0; ni < 2; ++ni)
          acc[mi][ni] = __builtin_amdgcn_mfma_f32_16x16x32_bf16(af[mi], bfv[ni], acc[mi][ni], 0, 0, 0);
      __builtin_amdgcn_s_setprio(0);
    }
    __syncthreads();
  }

  float bvv[2];
#pragma unroll
  for (int ni = 0; ni < 2; ++ni) bvv[ni] = bias[n0 + (wv << 5) + (ni << 4) + l15];
#pragma unroll
  for (int mi = 0; mi < 4; ++mi) {
    int m = m0 + (mi << 4) + ((lane >> 4) << 2);
#pragma unroll
    for (int ni = 0; ni < 2; ++ni) {
      int col = n0 + (wv << 5) + (ni << 4) + l15;
#pragma unroll
      for (int r = 0; r < 4; ++r)
        C[(size_t)(m + r) * MD + col] = acc[mi][ni][r] + bvv[ni];
    }
  }
}

// ---------------- flash attention: all-fragment 32x32, 4-deep prefetch -----
// R18 structure (48.2us best) with the ONLY change: register prefetch deepened
// from 2 buffers (1 chunk ahead ~250cyc) to 4 buffers (3 chunks ahead ~750cyc)
// to cover L2 load latency — the residual stall after TLP x4 / L1-traffic x0.5
// / manual-ILP all measured flat (R22/R23). grid 512 = b*h*qtile(16 of 128q),
// XCD swizzle; block 256 = 4 waves x 32 q; launch_bounds(256,2) keeps the
// allocator loose (VGPR ~190 < 256, no spill; 2 blocks/CU).
__global__ __launch_bounds__(256, 2)
void attn_kernel(const bf16_t* __restrict__ Q, const bf16_t* __restrict__ Kf,
                 const bf16_t* __restrict__ Vf, const float* __restrict__ nmask,
                 bf16_t* __restrict__ O) {
  int bid = (int)blockIdx.x;
  int lb  = (bid & 7) * 64 + (bid >> 3);   // 512 = 8 x 64, bijective
  const int tid  = threadIdx.x;
  const int lane = tid & 63;
  const int w    = tid >> 6;
  const int qt   = lb & 15;
  const int h    = (lb >> 4) & 15;
  const int b    = lb >> 8;
  const int q0w  = (qt << 7) + (w << 5);
  const int l31  = lane & 31;
  const int hi   = lane >> 5;

  // Q B-frags: lane holds Q[q=l31][d = s4*16 + hi*8 + j]
  bf16x8 qa[4];
  {
    const bf16_t* qp = Q + (size_t)(b * SEQL + q0w + l31) * MD + h * HDIM + (hi << 3);
#pragma unroll
    for (int s4 = 0; s4 < 4; ++s4) qa[s4] = *(const bf16x8*)(qp + (s4 << 4));
  }

  const bf16_t* KfB = Kf + (size_t)((b << 4) + h) * 131072;
  const bf16_t* VfB = Vf + (size_t)((b << 4) + h) * 131072;

  f32x16 oacc0 = {};   // d 0-31
  f32x16 oacc1 = {};   // d 32-63
  float lrun = 0.0f;

  bf16x8 k0[4], v0[4], k1[4], v1[4], k2[4], v2[4], k3[4], v3[4];

  auto LDKV = [&](int c, bf16x8* kf, bf16x8* vf) {
    const bf16_t* kp = KfB + (size_t)c * 2048 + (lane << 3);
    const bf16_t* vp = VfB + (size_t)c * 2048 + (lane << 3);
#pragma unroll
    for (int s4 = 0; s4 < 4; ++s4) kf[s4] = *(const bf16x8*)(kp + (s4 << 9));
#pragma unroll
    for (int u = 0; u < 4; ++u)   vf[u] = *(const bf16x8*)(vp + (u << 9));
  };

  auto BLK = [&](bf16x8* kf, bf16x8* vf) {
    f32x16 sacc = {};
    __builtin_amdgcn_s_setprio(1);
#pragma unroll
    for (int s4 = 0; s4 < 4; ++s4)
      sacc = __builtin_amdgcn_mfma_f32_32x32x16_bf16(kf[s4], qa[s4], sacc, 0, 0, 0);
    __builtin_amdgcn_s_setprio(0);
    float e[16];
#pragma unroll
    for (int r = 0; r < 16; ++r) e[r] = FEXP2(sacc[r]);
    lrun += ((e[0] + e[1]) + (e[2] + e[3])) + ((e[4] + e[5]) + (e[6] + e[7]))
          + ((e[8] + e[9]) + (e[10] + e[11])) + ((e[12] + e[13]) + (e[14] + e[15]));
    // P -> PV A-frags (kv 0-15 and 16-31) via cvt_pk + permlane32_swap
    unsigned x1 = cvtpk(e[0], e[1]),  x2 = cvtpk(e[2], e[3]);
    unsigned y1 = cvtpk(e[4], e[5]),  y2 = cvtpk(e[6], e[7]);
    unsigned z1 = cvtpk(e[8], e[9]),  z2 = cvtpk(e[10], e[11]);
    unsigned w1 = cvtpk(e[12], e[13]), w2 = cvtpk(e[14], e[15]);
    asm("v_permlane32_swap_b32 %0, %1" : "+v"(x1), "+v"(y1));
    asm("v_permlane32_swap_b32 %0, %1" : "+v"(x2), "+v"(y2));
    asm("v_permlane32_swap_b32 %0, %1" : "+v"(z1), "+v"(w1));
    asm("v_permlane32_swap_b32 %0, %1" : "+v"(z2), "+v"(w2));
    union { unsigned u[4]; bf16x8 v; } p0, p1;
    p0.u[0] = x1; p0.u[1] = x2; p0.u[2] = y1; p0.u[3] = y2;
    p1.u[0] = z1; p1.u[1] = z2; p1.u[2] = w1; p1.u[3] = w2;
    __builtin_amdgcn_s_setprio(1);
    oacc0 = __builtin_amdgcn_mfma_f32_32x32x16_bf16(p0.v, vf[0], oacc0, 0, 0, 0);
    oacc1 = __builtin_amdgcn_mfma_f32_32x32x16_bf16(p0.v, vf[1], oacc1, 0, 0, 0);
    oacc0 = __builtin_amdgcn_mfma_f32_32x32x16_bf16(p1.v, vf[2], oacc0, 0, 0, 0);
    oacc1 = __builtin_amdgcn_mfma_f32_32x32x16_bf16(p1.v, vf[3], oacc1, 0, 0, 0);
    __builtin_amdgcn_s_setprio(0);
  };

  // 4-deep rotation: loads stay 3 chunks ahead of use (~750cyc > L2 latency)
  LDKV(0, k0, v0);
  LDKV(1, k1, v1);
  LDKV(2, k2, v2);
  for (int ii = 0; ii < 16; ++ii) {
    const int c = ii << 2;
    LDKV(c + 3, k3, v3);                 BLK(k0, v0);
    if (c + 4 < 64) LDKV(c + 4, k0, v0); BLK(k1, v1);
    if (c + 5 < 64) LDKV(c + 5, k1, v1); BLK(k2, v2);
    if (c + 6 < 64) LDKV(c + 6, k2, v2); BLK(k3, v3);
  }

  // epilogue: combine hi halves of lrun, normalize, store O (row-major bf16)
  lrun += __shfl_xor(lrun, 32);
  float linv = 1.0f / (lrun - nmask[b]);
#pragma unroll
  for (int r = 0; r < 16; ++r) {
    int q = (r & 3) + ((r >> 2) << 3) + (hi << 2);
    float lr = __shfl(linv, q);
    size_t ro = (size_t)(b * SEQL + q0w + q) * MD + h * HDIM;
    O[ro + l31]      = (bf16_t)(oacc0[r] * lr);
    O[ro + 32 + l31] = (bf16_t)(oacc1[r] * lr);
  }
}

// ---------------- launch ----------------
extern "C" void kernel_launch(void* const* d_in, const int* in_sizes, int n_in,
                              void* d_out, int out_size, void* d_ws, size_t ws_size,
                              hipStream_t stream) {
  const float* in_k = (const float*)d_in[0];
  const float* in_q = (const float*)d_in[1];
  const float* in_v = (const float*)d_in[2];
  const float* mask = (const float*)d_in[3];
  const float* Wq   = (const float*)d_in[4];
  const float* bq   = (const float*)d_in[5];
  const float* Wk   = (const float*)d_in[6];
  const float* bk   = (const float*)d_in[7];
  const float* Wv   = (const float*)d_in[8];
  const float* bv   = (const float*)d_in[9];
  const float* Wo   = (const float*)d_in[10];
  const float* bo   = (const float*)d_in[11];

  const size_t XN = (size_t)MROWS * MD;   // 4,194,304 elems
  const size_t WN = (size_t)MD * MD;      // 1,048,576 elems
  char* w = (char*)d_ws;
  size_t off = 0;
  auto alloc = [&](size_t bytes) { char* p = w + off; off += bytes; return p; };
  bf16_t* xq    = (bf16_t*)alloc(XN * 2);
  bf16_t* xk    = (bf16_t*)alloc(XN * 2);
  bf16_t* xv    = (bf16_t*)alloc(XN * 2);
  bf16_t* wqb   = (bf16_t*)alloc(WN * 2);
  bf16_t* wkb   = (bf16_t*)alloc(WN * 2);
  bf16_t* wvb   = (bf16_t*)alloc(WN * 2);
  bf16_t* wob   = (bf16_t*)alloc(WN * 2);
  bf16_t* Qp    = (bf16_t*)alloc(XN * 2);
  bf16_t* Kfp   = (bf16_t*)alloc(XN * 2 + 8192);   // + pad for prefetch overrun
  bf16_t* Vfp   = (bf16_t*)alloc(XN * 2 + 8192);
  float*  bqs   = (float*)alloc(MD * 4);
  float*  nmask = (float*)alloc(16);
  bf16_t* attn  = xq;  // alias: xq is dead after gemm_qkv
  (void)ws_size;

  // single consolidated convert (3 X + 4 W + bqs + nmask)
  cvt_all<<<16387, 256, 0, stream>>>(in_q, in_k, in_v, Wq, Wk, Wv, Wo, mask, bq,
                                     (unsigned short*)xq, (unsigned short*)xk, (unsigned short*)xv,
                                     (unsigned short*)wqb, (unsigned short*)wkb,
                                     (unsigned short*)wvb, (unsigned short*)wob, bqs, nmask);

  // fused QKV projection; K/V written in MFMA fragment layouts
  gemm_qkv<<<768, 256, 0, stream>>>(xq, xk, xv, wqb, wkb, wvb, bqs, bk, bv, mask, Qp, Kfp, Vfp);

  // flash attention: 512 blocks x 4 waves x 32 q, 4-deep register prefetch
  attn_kernel<<<512, 256, 0, stream>>>(Qp, Kfp, Vfp, nmask, attn);

  // output projection -> fp32 d_out (64x128 tiles, 2 blocks/CU)
  gemm_out64<<<512, 256, 0, stream>>>(attn, wob, bo, (float*)d_out);
}

// Round 25
// 118.127 us; speedup vs baseline: 1.4319x; 1.0022x over previous
//
#include <hip/hip_runtime.h>
#include <hip/hip_bf16.h>
#include <stdint.h>

// Problem dims (fixed)
#define MD    1024      // model dim
#define NHEAD 16
#define HDIM  64
#define BSZ   2
#define SEQL  2048
#define MROWS 4096      // BSZ*SEQL

#define SCL2E 0.18033688011112042f   // (1/sqrt(64)) * log2(e), folded into Wq/bq

typedef __bf16 bf16_t;
typedef __bf16  bf16x8 __attribute__((ext_vector_type(8)));
typedef float   f32x4  __attribute__((ext_vector_type(4)));
typedef float   f32x16 __attribute__((ext_vector_type(16)));

// raw v_exp_f32 via compiler-visible builtin (hazards handled by backend).
#if __has_builtin(__builtin_amdgcn_exp2f)
  #define FEXP2(x) __builtin_amdgcn_exp2f(x)
#else
  #define FEXP2(x) exp2f(x)
#endif

// Async global->LDS, 16B per lane. LDS dest is wave-uniform base (+lane*16 by HW).
__device__ __forceinline__ void gload_lds16(const void* g, void* l) {
  __builtin_amdgcn_global_load_lds((const __attribute__((address_space(1))) void*)g,
                                   (__attribute__((address_space(3))) void*)l,
                                   16, 0, 0);
}

__device__ __forceinline__ unsigned short f2bf(float f) {
  unsigned u = __builtin_bit_cast(unsigned, f);
  u += 0x7fffu + ((u >> 16) & 1u);          // round-to-nearest-even
  return (unsigned short)(u >> 16);
}

// packed 2xf32 -> 2xbf16 in one dword (src0 -> low half)
__device__ __forceinline__ unsigned cvtpk(float a, float b) {
  unsigned r;
  asm("v_cvt_pk_bf16_f32 %0, %1, %2" : "=v"(r) : "v"(a), "v"(b));
  return r;
}

// ---------------- consolidated convert ----------------
// grid 16387: [0,12288) X (4096 each), [12288,16384) W (1024 each; Wq scaled),
// 16384: bq*SCL2E -> bqs ; 16385/16386: nmask[b] = sum(1-mask[b][:])
__global__ __launch_bounds__(256)
void cvt_all(const float* __restrict__ q, const float* __restrict__ k, const float* __restrict__ v,
             const float* __restrict__ wq, const float* __restrict__ wk,
             const float* __restrict__ wv, const float* __restrict__ wo,
             const float* __restrict__ mask, const float* __restrict__ bq,
             unsigned short* __restrict__ xq, unsigned short* __restrict__ xk, unsigned short* __restrict__ xv,
             unsigned short* __restrict__ wqb, unsigned short* __restrict__ wkb,
             unsigned short* __restrict__ wvb, unsigned short* __restrict__ wob,
             float* __restrict__ bqs, float* __restrict__ nmask) {
  int bx = blockIdx.x;
  if (bx >= 16384) {
    if (bx == 16384) {                    // bqs = bq * SCL2E (1024 floats)
      int i = threadIdx.x;
      float4 val = ((const float4*)bq)[i];
      float4 o;
      o.x = val.x * SCL2E; o.y = val.y * SCL2E; o.z = val.z * SCL2E; o.w = val.w * SCL2E;
      ((float4*)bqs)[i] = o;
    } else {                              // nmask[b]
      int b = bx - 16385;
      const float* mp = mask + b * SEQL + threadIdx.x * 8;
      float s = 0.0f;
#pragma unroll
      for (int j = 0; j < 8; ++j) s += 1.0f - mp[j];
      for (int d = 1; d < 64; d <<= 1) s += __shfl_xor(s, d);
      __shared__ float wsum[4];
      if ((threadIdx.x & 63) == 0) wsum[threadIdx.x >> 6] = s;
      __syncthreads();
      if (threadIdx.x == 0) nmask[b] = wsum[0] + wsum[1] + wsum[2] + wsum[3];
    }
    return;
  }
  const float* in; unsigned short* out; int i;
  float scale = 1.0f;
  if (bx < 12288) {
    int t = bx >> 12;
    in  = (t == 0) ? q : (t == 1) ? k : v;
    out = (t == 0) ? xq : (t == 1) ? xk : xv;
    i = (bx & 4095) * 256 + threadIdx.x;
  } else {
    int t = (bx - 12288) >> 10;
    in  = (t == 0) ? wq : (t == 1) ? wk : (t == 2) ? wv : wo;
    out = (t == 0) ? wqb : (t == 1) ? wkb : (t == 2) ? wvb : wob;
    if (t == 0) scale = SCL2E;
    i = (bx & 1023) * 256 + threadIdx.x;
  }
  float4 val = ((const float4*)in)[i];
  ushort4 o;
  o.x = f2bf(val.x * scale); o.y = f2bf(val.y * scale);
  o.z = f2bf(val.z * scale); o.w = f2bf(val.w * scale);
  ((ushort4*)out)[i] = o;
}

// ---------------- GEMM: C[m,n] = sum_k A[m,k]*B[n,k] + bias[n] ----------------
// 128x128 tile, BK=64, 4 waves (2x2 of 64x64), 16x16x32 bf16 MFMA.
// SHARED BUFFER IS PASSED IN (declared once per kernel!).
// MODE: 0 = bf16 row-major [m][n], optional runtime row-mask;
//       1 = f32 row-major;
//       2 = bf16 V in PV(32x32x16) B-frag layout, row-masked;
//       3 = bf16 K in QKt(32x32x16) A-frag layout, row-masked.
template<int MODE>
__device__ __forceinline__ void gemm_body(char* __restrict__ sm,
                                          const bf16_t* __restrict__ A,
                                          const bf16_t* __restrict__ Bm,
                                          const float*  __restrict__ bias,
                                          const float*  __restrict__ mask,
                                          void* __restrict__ Cout, int tile) {
  char* lsA = sm;
  char* lsB = sm + 16384;
  const int tid  = threadIdx.x;
  const int lane = tid & 63;
  const int wv   = tid >> 6;
  const int wm   = wv >> 1, wn = wv & 1;
  const int m0   = (tile >> 3) << 7;   // 32 m-tiles
  const int n0   = (tile & 7)  << 7;   // 8 n-tiles
  const int l15  = lane & 15;
  const int g16  = (lane >> 4) << 4;   // k-group byte base

  f32x4 acc[4][4] = {};

  for (int kk = 0; kk < MD; kk += 64) {
#pragma unroll
    for (int i = 0; i < 4; ++i) {
      int ch  = (wv << 2) + i;
      int o   = ch * 1024 + (lane << 4);
      int row = o >> 7;
      int scb = (o & 127) ^ ((row & 7) << 4);   // pre-swizzled source column byte
      const char* gA = (const char*)A  + (((size_t)(m0 + row) * MD + kk) << 1) + scb;
      const char* gB = (const char*)Bm + (((size_t)(n0 + row) * MD + kk) << 1) + scb;
      gload_lds16(gA, lsA + ch * 1024);
      gload_lds16(gB, lsB + ch * 1024);
    }
    __syncthreads();
#pragma unroll
    for (int s = 0; s < 2; ++s) {
      bf16x8 af[4], bfv[4];
#pragma unroll
      for (int mi = 0; mi < 4; ++mi) {
        int r  = (wm << 6) + (mi << 4) + l15;
        int cb = (g16 + (s << 6)) ^ ((r & 7) << 4);
        af[mi] = *(const bf16x8*)(lsA + (r << 7) + cb);
      }
#pragma unroll
      for (int ni = 0; ni < 4; ++ni) {
        int r  = (wn << 6) + (ni << 4) + l15;
        int cb = (g16 + (s << 6)) ^ ((r & 7) << 4);
        bfv[ni] = *(const bf16x8*)(lsB + (r << 7) + cb);
      }
      __builtin_amdgcn_s_setprio(1);
#pragma unroll
      for (int mi = 0; mi < 4; ++mi)
#pragma unroll
        for (int ni = 0; ni < 4; ++ni)
          acc[mi][ni] = __builtin_amdgcn_mfma_f32_16x16x32_bf16(af[mi], bfv[ni], acc[mi][ni], 0, 0, 0);
      __builtin_amdgcn_s_setprio(0);
    }
    __syncthreads();
  }

  // epilogue: C/D layout col = lane&15, row = (lane>>4)*4 + reg
  float bvv[4];
#pragma unroll
  for (int ni = 0; ni < 4; ++ni) bvv[ni] = bias[n0 + (wn << 6) + (ni << 4) + l15];
#pragma unroll
  for (int mi = 0; mi < 4; ++mi) {
    int m = m0 + (wm << 6) + (mi << 4) + ((lane >> 4) << 2);  // token rows m..m+3
    float4 mk = {1.0f, 1.0f, 1.0f, 1.0f};
    if constexpr (MODE == 2 || MODE == 3) mk = *(const float4*)&mask[m];
    if constexpr (MODE == 0) { if (mask) mk = *(const float4*)&mask[m]; }
#pragma unroll
    for (int ni = 0; ni < 4; ++ni) {
      int col = n0 + (wn << 6) + (ni << 4) + l15;
      if constexpr (MODE == 2) {
        // V PV-B-frag layout; 4 consecutive kv -> 4 contiguous elems (8B store)
        int b2 = m >> 11; int kv = m & 2047;
        int hh = col >> 6; int dd = col & 63;
        int dl = (dd >> 5) & 1; int dcol = dd & 31;
        size_t base = (size_t)((b2 << 4) + hh) * 131072 + (size_t)(kv >> 5) * 2048
                    + (size_t)((((kv >> 4) & 1) << 1) + dl) * 512
                    + (size_t)((((kv >> 3) & 1) << 5) + dcol) * 8 + (kv & 7);
        ushort4 pk;
        pk.x = f2bf((acc[mi][ni][0] + bvv[ni]) * mk.x);
        pk.y = f2bf((acc[mi][ni][1] + bvv[ni]) * mk.y);
        pk.z = f2bf((acc[mi][ni][2] + bvv[ni]) * mk.z);
        pk.w = f2bf((acc[mi][ni][3] + bvv[ni]) * mk.w);
        *(ushort4*)((unsigned short*)Cout + base) = pk;
      } else if constexpr (MODE == 3) {
        // K QKt-A-frag layout; 4 consecutive kv -> stride-8 scalar stores
        int b2 = m >> 11; int kv = m & 2047;
        int hh = col >> 6; int dd = col & 63;
        size_t base = (size_t)((b2 << 4) + hh) * 131072 + (size_t)(kv >> 5) * 2048
                    + (size_t)(dd >> 4) * 512
                    + (size_t)((((dd >> 3) & 1) << 5) + (kv & 31)) * 8 + (dd & 7);
#pragma unroll
        for (int r = 0; r < 4; ++r)
          ((unsigned short*)Cout)[base + ((size_t)r << 3)] =
              f2bf((acc[mi][ni][r] + bvv[ni]) * ((const float*)&mk)[r]);
      } else {
#pragma unroll
        for (int r = 0; r < 4; ++r) {
          float vv = acc[mi][ni][r] + bvv[ni];
          if constexpr (MODE == 0) vv *= ((const float*)&mk)[r];
          if constexpr (MODE == 1) ((float*)Cout)[(size_t)(m + r) * MD + col] = vv;
          else                     ((bf16_t*)Cout)[(size_t)(m + r) * MD + col] = (bf16_t)vv;
        }
      }
    }
  }
}

// fused QKV (768 blocks): Q row-major pre-scaled; K -> Kf frags; V -> Vf frags.
// launch_bounds(256,4): VGPR was 132 at bound 3 — a 4-reg squeeze to the 128
// tier buys 4 blocks/CU (vs 3). Unlike R21's attn (110 live vs 64 cap =
// catastrophic spill), 132->128 is marginal rematerialization.
__global__ __launch_bounds__(256, 4)
void gemm_qkv(const bf16_t* __restrict__ xq, const bf16_t* __restrict__ xk, const bf16_t* __restrict__ xv,
              const bf16_t* __restrict__ wq, const bf16_t* __restrict__ wk, const bf16_t* __restrict__ wv_,
              const float* __restrict__ bqs, const float* __restrict__ bk, const float* __restrict__ bv,
              const float* __restrict__ mask,
              bf16_t* __restrict__ Qo, bf16_t* __restrict__ Kfo, bf16_t* __restrict__ Vfo) {
  __shared__ __align__(1024) char sm[32768];
  int t = blockIdx.x & 255;
  int g = blockIdx.x >> 8;
  if (g == 0)      gemm_body<0>(sm, xq, wq,  bqs, nullptr, Qo,  t);
  else if (g == 1) gemm_body<3>(sm, xk, wk,  bk,  mask,    Kfo, t);
  else             gemm_body<2>(sm, xv, wv_, bv,  mask,    Vfo, t);
}

// output projection, 64x128 tiles -> 512 blocks = 2 blocks/CU.
__global__ __launch_bounds__(256, 2)
void gemm_out64(const bf16_t* __restrict__ A, const bf16_t* __restrict__ Bm,
                const float* __restrict__ bias, float* __restrict__ C) {
  __shared__ __align__(1024) char sm[24576];
  char* lsA = sm;           // 64 rows x 128B
  char* lsB = sm + 8192;    // 128 rows x 128B
  const int tile = (int)blockIdx.x;
  const int m0   = (tile >> 3) << 6;   // 64 m-tiles
  const int n0   = (tile & 7)  << 7;   // 8 n-tiles
  const int tid  = threadIdx.x;
  const int lane = tid & 63;
  const int wv   = tid >> 6;
  const int l15  = lane & 15;
  const int g16  = (lane >> 4) << 4;

  f32x4 acc[4][2] = {};

  for (int kk = 0; kk < MD; kk += 64) {
#pragma unroll
    for (int i = 0; i < 6; ++i) {
      int ch = wv * 6 + i;             // 24 chunks: 0-7 A, 8-23 B
      if (ch < 8) {
        int o   = ch * 1024 + (lane << 4);
        int row = o >> 7;
        int scb = (o & 127) ^ ((row & 7) << 4);
        gload_lds16((const char*)A + (((size_t)(m0 + row) * MD + kk) << 1) + scb,
                    lsA + ch * 1024);
      } else {
        int cl  = ch - 8;
        int o   = cl * 1024 + (lane << 4);
        int row = o >> 7;
        int scb = (o & 127) ^ ((row & 7) << 4);
        gload_lds16((const char*)Bm + (((size_t)(n0 + row) * MD + kk) << 1) + scb,
                    lsB + cl * 1024);
      }
    }
    __syncthreads();
#pragma unroll
    for (int s = 0; s < 2; ++s) {
      bf16x8 af[4], bfv[2];
#pragma unroll
      for (int mi = 0; mi < 4; ++mi) {
        int r  = (mi << 4) + l15;
        int cb = (g16 + (s << 6)) ^ ((r & 7) << 4);
        af[mi] = *(const bf16x8*)(lsA + (r << 7) + cb);
      }
#pragma unroll
      for (int ni = 0; ni < 2; ++ni) {
        int r  = (wv << 5) + (ni << 4) + l15;
        int cb = (g16 + (s << 6)) ^ ((r & 7) << 4);
        bfv[ni] = *(const bf16x8*)(lsB + (r << 7) + cb);
      }
      __builtin_amdgcn_s_setprio(1);
#pragma unroll
      for (int mi = 0; mi < 4; ++mi)
#pragma unroll
        for (int ni = 0; ni < 2; ++ni)
          acc[mi][ni] = __builtin_amdgcn_mfma_f32_16x16x32_bf16(af[mi], bfv[ni], acc[mi][ni], 0, 0, 0);
      __builtin_amdgcn_s_setprio(0);
    }
    __syncthreads();
  }

  float bvv[2];
#pragma unroll
  for (int ni = 0; ni < 2; ++ni) bvv[ni] = bias[n0 + (wv << 5) + (ni << 4) + l15];
#pragma unroll
  for (int mi = 0; mi < 4; ++mi) {
    int m = m0 + (mi << 4) + ((lane >> 4) << 2);
#pragma unroll
    for (int ni = 0; ni < 2; ++ni) {
      int col = n0 + (wv << 5) + (ni << 4) + l15;
#pragma unroll
      for (int r = 0; r < 4; ++r)
        C[(size_t)(m + r) * MD + col] = acc[mi][ni][r] + bvv[ni];
    }
  }
}

// ---------------- flash attention: all-fragment 32x32, zero LDS/barriers ----
// R18 structure EXACTLY (best measured 48.2us; deeper prefetch/TLP/ILP all
// measured flat — characterized structural plateau at MfmaUtil ~30%).
// grid 512 = b(2)*h(16)*qtile(16 of 128q), XCD swizzle; block 256 = 4 waves,
// each wave owns 32 q and sweeps ALL kv in 64 chunks of 32. Ping-pong
// prefetch one chunk ahead; compiler schedules the interleave.
// Swapped QK^T: softmax lane-local (no-max builtin v_exp_f32, deferred
// reduce). P assembled in regs via cvt_pk + permlane32_swap.
__global__ __launch_bounds__(256, 2)
void attn_kernel(const bf16_t* __restrict__ Q, const bf16_t* __restrict__ Kf,
                 const bf16_t* __restrict__ Vf, const float* __restrict__ nmask,
                 bf16_t* __restrict__ O) {
  int bid = (int)blockIdx.x;
  int lb  = (bid & 7) * 64 + (bid >> 3);   // 512 = 8 x 64, bijective
  const int tid  = threadIdx.x;
  const int lane = tid & 63;
  const int w    = tid >> 6;
  const int qt   = lb & 15;
  const int h    = (lb >> 4) & 15;
  const int b    = lb >> 8;
  const int q0w  = (qt << 7) + (w << 5);
  const int l31  = lane & 31;
  const int hi   = lane >> 5;

  // Q B-frags: lane holds Q[q=l31][d = s4*16 + hi*8 + j]
  bf16x8 qa[4];
  {
    const bf16_t* qp = Q + (size_t)(b * SEQL + q0w + l31) * MD + h * HDIM + (hi << 3);
#pragma unroll
    for (int s4 = 0; s4 < 4; ++s4) qa[s4] = *(const bf16x8*)(qp + (s4 << 4));
  }

  const bf16_t* KfB = Kf + (size_t)((b << 4) + h) * 131072;
  const bf16_t* VfB = Vf + (size_t)((b << 4) + h) * 131072;

  f32x16 oacc0 = {};   // d 0-31
  f32x16 oacc1 = {};   // d 32-63
  float lrun = 0.0f;

  bf16x8 kA[4], vA[4], kB[4], vB[4];

  auto LDKV = [&](int c, bf16x8* kf, bf16x8* vf) {
    const bf16_t* kp = KfB + (size_t)c * 2048 + (lane << 3);
    const bf16_t* vp = VfB + (size_t)c * 2048 + (lane << 3);
#pragma unroll
    for (int s4 = 0; s4 < 4; ++s4) kf[s4] = *(const bf16x8*)(kp + (s4 << 9));
#pragma unroll
    for (int u = 0; u < 4; ++u)   vf[u] = *(const bf16x8*)(vp + (u << 9));
  };

  auto BLK = [&](bf16x8* kf, bf16x8* vf) {
    f32x16 sacc = {};
    __builtin_amdgcn_s_setprio(1);
#pragma unroll
    for (int s4 = 0; s4 < 4; ++s4)
      sacc = __builtin_amdgcn_mfma_f32_32x32x16_bf16(kf[s4], qa[s4], sacc, 0, 0, 0);
    __builtin_amdgcn_s_setprio(0);
    float e[16];
#pragma unroll
    for (int r = 0; r < 16; ++r) e[r] = FEXP2(sacc[r]);
    lrun += ((e[0] + e[1]) + (e[2] + e[3])) + ((e[4] + e[5]) + (e[6] + e[7]))
          + ((e[8] + e[9]) + (e[10] + e[11])) + ((e[12] + e[13]) + (e[14] + e[15]));
    // P -> PV A-frags (kv 0-15 and 16-31) via cvt_pk + permlane32_swap
    unsigned x1 = cvtpk(e[0], e[1]),  x2 = cvtpk(e[2], e[3]);
    unsigned y1 = cvtpk(e[4], e[5]),  y2 = cvtpk(e[6], e[7]);
    unsigned z1 = cvtpk(e[8], e[9]),  z2 = cvtpk(e[10], e[11]);
    unsigned w1 = cvtpk(e[12], e[13]), w2 = cvtpk(e[14], e[15]);
    asm("v_permlane32_swap_b32 %0, %1" : "+v"(x1), "+v"(y1));
    asm("v_permlane32_swap_b32 %0, %1" : "+v"(x2), "+v"(y2));
    asm("v_permlane32_swap_b32 %0, %1" : "+v"(z1), "+v"(w1));
    asm("v_permlane32_swap_b32 %0, %1" : "+v"(z2), "+v"(w2));
    union { unsigned u[4]; bf16x8 v; } p0, p1;
    p0.u[0] = x1; p0.u[1] = x2; p0.u[2] = y1; p0.u[3] = y2;
    p1.u[0] = z1; p1.u[1] = z2; p1.u[2] = w1; p1.u[3] = w2;
    __builtin_amdgcn_s_setprio(1);
    oacc0 = __builtin_amdgcn_mfma_f32_32x32x16_bf16(p0.v, vf[0], oacc0, 0, 0, 0);
    oacc1 = __builtin_amdgcn_mfma_f32_32x32x16_bf16(p0.v, vf[1], oacc1, 0, 0, 0);
    oacc0 = __builtin_amdgcn_mfma_f32_32x32x16_bf16(p1.v, vf[2], oacc0, 0, 0, 0);
    oacc1 = __builtin_amdgcn_mfma_f32_32x32x16_bf16(p1.v, vf[3], oacc1, 0, 0, 0);
    __builtin_amdgcn_s_setprio(0);
  };

  LDKV(0, kA, vA);
  for (int ii = 0; ii < 32; ++ii) {
    LDKV((ii << 1) + 1, kB, vB);
    BLK(kA, vA);
    LDKV((ii << 1) + 2, kA, vA);   // ii=31 reads pad block 64 (harmless)
    BLK(kB, vB);
  }

  // epilogue: combine hi halves of lrun, normalize, store O (row-major bf16)
  lrun += __shfl_xor(lrun, 32);
  float linv = 1.0f / (lrun - nmask[b]);
#pragma unroll
  for (int r = 0; r < 16; ++r) {
    int q = (r & 3) + ((r >> 2) << 3) + (hi << 2);
    float lr = __shfl(linv, q);
    size_t ro = (size_t)(b * SEQL + q0w + q) * MD + h * HDIM;
    O[ro + l31]      = (bf16_t)(oacc0[r] * lr);
    O[ro + 32 + l31] = (bf16_t)(oacc1[r] * lr);
  }
}

// ---------------- launch ----------------
extern "C" void kernel_launch(void* const* d_in, const int* in_sizes, int n_in,
                              void* d_out, int out_size, void* d_ws, size_t ws_size,
                              hipStream_t stream) {
  const float* in_k = (const float*)d_in[0];
  const float* in_q = (const float*)d_in[1];
  const float* in_v = (const float*)d_in[2];
  const float* mask = (const float*)d_in[3];
  const float* Wq   = (const float*)d_in[4];
  const float* bq   = (const float*)d_in[5];
  const float* Wk   = (const float*)d_in[6];
  const float* bk   = (const float*)d_in[7];
  const float* Wv   = (const float*)d_in[8];
  const float* bv   = (const float*)d_in[9];
  const float* Wo   = (const float*)d_in[10];
  const float* bo   = (const float*)d_in[11];

  const size_t XN = (size_t)MROWS * MD;   // 4,194,304 elems
  const size_t WN = (size_t)MD * MD;      // 1,048,576 elems
  char* w = (char*)d_ws;
  size_t off = 0;
  auto alloc = [&](size_t bytes) { char* p = w + off; off += bytes; return p; };
  bf16_t* xq    = (bf16_t*)alloc(XN * 2);
  bf16_t* xk    = (bf16_t*)alloc(XN * 2);
  bf16_t* xv    = (bf16_t*)alloc(XN * 2);
  bf16_t* wqb   = (bf16_t*)alloc(WN * 2);
  bf16_t* wkb   = (bf16_t*)alloc(WN * 2);
  bf16_t* wvb   = (bf16_t*)alloc(WN * 2);
  bf16_t* wob   = (bf16_t*)alloc(WN * 2);
  bf16_t* Qp    = (bf16_t*)alloc(XN * 2);
  bf16_t* Kfp   = (bf16_t*)alloc(XN * 2 + 8192);   // + pad for prefetch overrun
  bf16_t* Vfp   = (bf16_t*)alloc(XN * 2 + 8192);
  float*  bqs   = (float*)alloc(MD * 4);
  float*  nmask = (float*)alloc(16);
  bf16_t* attn  = xq;  // alias: xq is dead after gemm_qkv
  (void)ws_size;

  // single consolidated convert (3 X + 4 W + bqs + nmask)
  cvt_all<<<16387, 256, 0, stream>>>(in_q, in_k, in_v, Wq, Wk, Wv, Wo, mask, bq,
                                     (unsigned short*)xq, (unsigned short*)xk, (unsigned short*)xv,
                                     (unsigned short*)wqb, (unsigned short*)wkb,
                                     (unsigned short*)wvb, (unsigned short*)wob, bqs, nmask);

  // fused QKV projection; K/V written in MFMA fragment layouts (4 blocks/CU)
  gemm_qkv<<<768, 256, 0, stream>>>(xq, xk, xv, wqb, wkb, wvb, bqs, bk, bv, mask, Qp, Kfp, Vfp);

  // flash attention: 512 blocks x 4 waves x 32 q, all-fragment, no LDS
  attn_kernel<<<512, 256, 0, stream>>>(Qp, Kfp, Vfp, nmask, attn);

  // output projection -> fp32 d_out (64x128 tiles, 2 blocks/CU)
  gemm_out64<<<512, 256, 0, stream>>>(attn, wob, bo, (float*)d_out);
}